// Round 10
// baseline (229.513 us; speedup 1.0000x reference)
//
#include <hip/hip_runtime.h>
#include <hip/hip_bf16.h>
#include <stdint.h>

#define DI __device__ __forceinline__

typedef __bf16 bf16x8 __attribute__((ext_vector_type(8)));
typedef float f32x4 __attribute__((ext_vector_type(4)));
typedef unsigned short ushortx8 __attribute__((ext_vector_type(8)));

// fp32 -> bf16 round-to-nearest-even (scalar path)
DI unsigned short f2bf(float f) {
    unsigned int u = __builtin_bit_cast(unsigned int, f);
    u += 0x7fffu + ((u >> 16) & 1u);
    return (unsigned short)(u >> 16);
}

// packed fp32x2 -> bf16x2 (1 VALU op). lo -> bits 0-15, hi -> bits 16-31.
DI unsigned int cvt_pk_bf16(float lo, float hi) {
    unsigned int r;
    asm("v_cvt_pk_bf16_f32 %0, %1, %2" : "=v"(r) : "v"(lo), "v"(hi));
    return r;
}

DI f32x4 mfma_16x16x32_bf16(bf16x8 a, bf16x8 b, f32x4 c) {
    return __builtin_amdgcn_mfma_f32_16x16x32_bf16(a, b, c, 0, 0, 0);
}

// async global->LDS, 16B per lane. LDS dest: wave-uniform base + lane*16.
DI void gload16(const unsigned short* g, unsigned short* l) {
    __builtin_amdgcn_global_load_lds(
        (const __attribute__((address_space(1))) void*)g,
        (__attribute__((address_space(3))) void*)l, 16, 0, 0);
}

// ---------------------------------------------------------------------------
// k_cvt: fp32 -> bf16 elementwise for Q, K, V (grid.y selects tensor).
// ---------------------------------------------------------------------------
__global__ __launch_bounds__(256) void k_cvt(
    const float* __restrict__ s0, const float* __restrict__ s1, const float* __restrict__ s2,
    unsigned short* __restrict__ d0, unsigned short* __restrict__ d1, unsigned short* __restrict__ d2)
{
    const int z = blockIdx.y;
    const float* s = z == 0 ? s0 : z == 1 ? s1 : s2;
    unsigned short* d = z == 0 ? d0 : z == 1 ? d1 : d2;
    const int i0 = blockIdx.x * 256 + threadIdx.x;
    #pragma unroll
    for (int it = 0; it < 4; ++it) {
        const int i = i0 + it * 262144;
        const float4 v = reinterpret_cast<const float4*>(s)[i];
        uint2 pk;
        pk.x = cvt_pk_bf16(v.x, v.y);
        pk.y = cvt_pk_bf16(v.z, v.w);
        reinterpret_cast<uint2*>(d)[i] = pk;
    }
}

// ---------------------------------------------------------------------------
// k_wt: W fp32 [1024][1024] -> Wt bf16 [n][k] (transposed), grid.z = 4 matrices.
// ---------------------------------------------------------------------------
__global__ __launch_bounds__(256) void k_wt(
    const float* __restrict__ w0, const float* __restrict__ w1,
    const float* __restrict__ w2, const float* __restrict__ w3,
    unsigned short* __restrict__ o0, unsigned short* __restrict__ o1,
    unsigned short* __restrict__ o2, unsigned short* __restrict__ o3)
{
    constexpr int N = 1024;
    const int z = blockIdx.z;
    const float* W = z == 0 ? w0 : z == 1 ? w1 : z == 2 ? w2 : w3;
    unsigned short* O = z == 0 ? o0 : z == 1 ? o1 : z == 2 ? o2 : o3;

    __shared__ unsigned short L[64 * 64];
    const int tid = threadIdx.x;
    const int k0 = blockIdx.x * 64, n0 = blockIdx.y * 64;

    const int r = tid >> 2, cbase = (tid & 3) * 16;
    #pragma unroll
    for (int i = 0; i < 4; ++i) {
        const int c = cbase + i * 4;
        const float4 v = *reinterpret_cast<const float4*>(&W[(size_t)(k0 + r) * N + n0 + c]);
        uint2 pk;
        pk.x = cvt_pk_bf16(v.x, v.y);
        pk.y = cvt_pk_bf16(v.z, v.w);
        const int byte = r * 128 + ((c * 2) ^ ((r & 7) << 4));
        *reinterpret_cast<uint2*>(reinterpret_cast<char*>(L) + byte) = pk;
    }
    __syncthreads();

    const int n = tid >> 2, kc = (tid & 3) * 16;
    ushortx8 v0, v1;
    #pragma unroll
    for (int j = 0; j < 8; ++j) {
        const int ka = kc + j, kb2 = kc + 8 + j;
        v0[j] = *reinterpret_cast<const unsigned short*>(
            reinterpret_cast<const char*>(L) + ka * 128 + ((n * 2) ^ ((ka & 7) << 4)));
        v1[j] = *reinterpret_cast<const unsigned short*>(
            reinterpret_cast<const char*>(L) + kb2 * 128 + ((n * 2) ^ ((kb2 & 7) << 4)));
    }
    unsigned short* op = &O[(size_t)(n0 + n) * N + k0 + kc];
    *reinterpret_cast<ushortx8*>(op) = v0;
    *reinterpret_cast<ushortx8*>(op + 8) = v1;
}

// ---------------------------------------------------------------------------
// m97-style bf16 GEMM -- REVERTED to the round-8 single-buffer form (proven
// 52.4 us; round-9 explicit dbuf regressed, cf. guide m99/m100).
// ---------------------------------------------------------------------------
template <int MODE>
__global__ __launch_bounds__(256) void k_gemm_bf16(
    const unsigned short* __restrict__ A0, const unsigned short* __restrict__ A1,
    const unsigned short* __restrict__ A2,
    const unsigned short* __restrict__ B0, const unsigned short* __restrict__ B1,
    const unsigned short* __restrict__ B2,
    const float* __restrict__ bias0, const float* __restrict__ bias1,
    const float* __restrict__ bias2,
    void* C0, void* C1, void* C2)
{
    constexpr int K = 1024, N = 1024;
    const int z = MODE ? blockIdx.z : 0;
    const unsigned short* A  = z == 0 ? A0 : z == 1 ? A1 : A2;
    const unsigned short* Bt = z == 0 ? B0 : z == 1 ? B1 : B2;
    const float* bias        = z == 0 ? bias0 : z == 1 ? bias1 : bias2;
    void* C                  = z == 0 ? C0 : z == 1 ? C1 : C2;

    __shared__ unsigned short As[128 * 32];
    __shared__ unsigned short Bs[128 * 32];

    const int tid  = threadIdx.x;
    const int lane = tid & 63;
    const int w    = tid >> 6;
    const int wr   = w >> 1, wc = w & 1;
    const int fr   = lane & 15, kg = lane >> 4;
    const int m0   = blockIdx.x * 128, n0 = blockIdx.y * 128;

    const int srow = lane >> 2;
    const int sk8  = (lane & 3) * 8;

    f32x4 acc[4][4] = {};

    for (int t = 0; t < K / 32; ++t) {
        const int k0 = t * 32;
        #pragma unroll
        for (int i = 0; i < 2; ++i) {
            const int c = w * 2 + i;
            const int row = c * 16 + srow;
            gload16(&A[(size_t)(m0 + row) * K + k0 + sk8], &As[c * 512]);
            gload16(&Bt[(size_t)(n0 + row) * K + k0 + sk8], &Bs[c * 512]);
        }
        __syncthreads();

        bf16x8 af[4], bfj[4];
        #pragma unroll
        for (int i = 0; i < 4; ++i)
            af[i] = *reinterpret_cast<const bf16x8*>(&As[(wr * 64 + i * 16 + fr) * 32 + kg * 8]);
        #pragma unroll
        for (int j = 0; j < 4; ++j)
            bfj[j] = *reinterpret_cast<const bf16x8*>(&Bs[(wc * 64 + j * 16 + fr) * 32 + kg * 8]);
        #pragma unroll
        for (int i = 0; i < 4; ++i)
            #pragma unroll
            for (int j = 0; j < 4; ++j)
                acc[i][j] = mfma_16x16x32_bf16(af[i], bfj[j], acc[i][j]);
        __syncthreads();
    }

    if (MODE == 1 && z == 2) {
        unsigned short* vt = reinterpret_cast<unsigned short*>(C);
        #pragma unroll
        for (int i = 0; i < 4; ++i) {
            const int m = m0 + wr * 64 + i * 16 + kg * 4;
            const int bb = m >> 11, s = m & 2047;
            #pragma unroll
            for (int j = 0; j < 4; ++j) {
                const int n = n0 + wc * 64 + j * 16 + fr;
                const float bv = bias[n];
                uint2 pk;
                pk.x = cvt_pk_bf16(acc[i][j][0] + bv, acc[i][j][1] + bv);
                pk.y = cvt_pk_bf16(acc[i][j][2] + bv, acc[i][j][3] + bv);
                *reinterpret_cast<uint2*>(&vt[((size_t)(bb * 1024 + n)) * 2048 + s]) = pk;
            }
        }
    } else if (MODE == 1) {
        const float sc = (z == 0) ? 0.125f : 1.0f;
        unsigned short* Cb = reinterpret_cast<unsigned short*>(C);
        #pragma unroll
        for (int i = 0; i < 4; ++i) {
            const int m = m0 + wr * 64 + i * 16 + kg * 4;
            #pragma unroll
            for (int j = 0; j < 4; ++j) {
                const int n = n0 + wc * 64 + j * 16 + fr;
                const float bv = bias[n];
                const unsigned int p0 = cvt_pk_bf16((acc[i][j][0] + bv) * sc, (acc[i][j][1] + bv) * sc);
                const unsigned int p1 = cvt_pk_bf16((acc[i][j][2] + bv) * sc, (acc[i][j][3] + bv) * sc);
                Cb[(size_t)(m + 0) * N + n] = (unsigned short)p0;
                Cb[(size_t)(m + 1) * N + n] = (unsigned short)(p0 >> 16);
                Cb[(size_t)(m + 2) * N + n] = (unsigned short)p1;
                Cb[(size_t)(m + 3) * N + n] = (unsigned short)(p1 >> 16);
            }
        }
    } else {
        float* Cf = reinterpret_cast<float*>(C);
        #pragma unroll
        for (int i = 0; i < 4; ++i) {
            const int m = m0 + wr * 64 + i * 16 + kg * 4;
            #pragma unroll
            for (int j = 0; j < 4; ++j) {
                const int n = n0 + wc * 64 + j * 16 + fr;
                const float bv = bias[n];
                #pragma unroll
                for (int r = 0; r < 4; ++r)
                    Cf[(size_t)(m + r) * N + n] = acc[i][j][r] + bv;
            }
        }
    }
}

// ---------------------------------------------------------------------------
// V tail suffix sums (unchanged).
// ---------------------------------------------------------------------------
__global__ __launch_bounds__(256) void k_vtail(
    const unsigned short* __restrict__ vt, float* __restrict__ vtail)
{
    const int row = blockIdx.x * 4 + (threadIdx.x >> 6);
    const int l = threadIdx.x & 63;
    const unsigned short* p = &vt[(size_t)row * 2048 + l * 32];
    float s = 0.f;
    #pragma unroll
    for (int i = 0; i < 4; ++i) {
        ushortx8 v = *reinterpret_cast<const ushortx8*>(&p[i * 8]);
        #pragma unroll
        for (int e = 0; e < 8; ++e)
            s += __builtin_bit_cast(float, (unsigned int)v[e] << 16);
    }
    #pragma unroll
    for (int off = 1; off < 64; off <<= 1) {
        const float t = __shfl_down(s, off, 64);
        s += (l + off < 64) ? t : 0.f;
    }
    float tv = __shfl(s, (2 * l + 2) & 63, 64);
    if (l == 31) tv = 0.f;
    if (l < 32) vtail[(size_t)row * 32 + l] = tv;
}

// ---------------------------------------------------------------------------
// Attention v7: NO K/V LDS staging -- fragments read directly from global
// (L2-resident: 512 KB per (b,h), shared by 16 blocks; Common-mistake #7).
// Zero __syncthreads in the sweep: P-LDS is per-wave (lgkm ordering only),
// so every wave streams independently -- no barrier drains at all.
// Causal pair balancing + swapped QK^T + V-tail substitution kept.
// ---------------------------------------------------------------------------
template <bool MASK>
DI void attn_tile_g(const unsigned short* __restrict__ kpT,   // K tile base [64][D]
                    const unsigned short* __restrict__ vtT,   // V^T tile base [.][S]+off
                    unsigned char* PB, bf16x8 qf0, bf16x8 qf1,
                    f32x4 (&o)[4], float& lsum, int w, int fr, int kg)
{
    constexpr int S = 2048, D = 1024;
    const int sw = (fr & 7) << 4;
    #pragma unroll
    for (int j = 0; j < 4; ++j) {
        const size_t roff = (size_t)(j * 16 + fr) * D + kg * 8;
        const bf16x8 kf0 = *reinterpret_cast<const bf16x8*>(&kpT[roff]);
        const bf16x8 kf1 = *reinterpret_cast<const bf16x8*>(&kpT[roff + 32]);
        f32x4 s = {0.f, 0.f, 0.f, 0.f};
        s = mfma_16x16x32_bf16(kf0, qf0, s);   // swapped: A=K rows (keys), B=Q
        s = mfma_16x16x32_bf16(kf1, qf1, s);
        float p[4];
        #pragma unroll
        for (int r = 0; r < 4; ++r) {
            float e = __expf(s[r]);
            if (MASK && (j * 16 + kg * 4 + r > w * 16 + fr)) e = 1.0f;  // exp(-1e-8)==1.0f
            p[r] = e;
            lsum += e;
        }
        uint2 pk;
        pk.x = cvt_pk_bf16(p[0], p[1]);
        pk.y = cvt_pk_bf16(p[2], p[3]);
        *reinterpret_cast<uint2*>(PB + fr * 128 + ((j * 32 + kg * 8) ^ sw)) = pk;
    }
    #pragma unroll
    for (int kk = 0; kk < 2; ++kk) {
        const bf16x8 pf = *reinterpret_cast<const bf16x8*>(PB + fr * 128 + ((kk * 64 + kg * 16) ^ sw));
        #pragma unroll
        for (int n = 0; n < 4; ++n) {
            const bf16x8 vf = *reinterpret_cast<const bf16x8*>(
                &vtT[(size_t)(n * 16 + fr) * S + kk * 32 + kg * 8]);
            o[n] = mfma_16x16x32_bf16(pf, vf, o[n]);
        }
    }
}

DI void attn_sweep(int qt,
                   const unsigned short* __restrict__ qp,
                   const unsigned short* __restrict__ kp,
                   const unsigned short* __restrict__ vt,
                   const float* __restrict__ vtail,
                   unsigned short* __restrict__ ctx,
                   unsigned char* PB, size_t baseQ, size_t baseV, int b, int h,
                   int w, int fr, int kg)
{
    constexpr int S = 2048, D = 1024;
    const int q0 = qt * 64 + w * 16;

    bf16x8 qf0, qf1;
    {
        const size_t roff = baseQ + (size_t)(q0 + fr) * D;
        qf0 = *reinterpret_cast<const bf16x8*>(&qp[roff + kg * 8]);
        qf1 = *reinterpret_cast<const bf16x8*>(&qp[roff + 32 + kg * 8]);
    }

    f32x4 o[4] = {};
    float lsum = 0.f;

    for (int t = 0; t < qt; ++t)
        attn_tile_g<false>(kp + baseQ + (size_t)t * 64 * D, vt + baseV + t * 64,
                           PB, qf0, qf1, o, lsum, w, fr, kg);
    attn_tile_g<true>(kp + baseQ + (size_t)qt * 64 * D, vt + baseV + qt * 64,
                      PB, qf0, qf1, o, lsum, w, fr, kg);

    // full row sums: combine the 4 key-groups, add analytic tail count
    lsum += __shfl_xor(lsum, 16, 64);
    lsum += __shfl_xor(lsum, 32, 64);
    lsum += (float)(S - (qt + 1) * 64);

    float lq[4];
    #pragma unroll
    for (int r = 0; r < 4; ++r) lq[r] = __shfl(lsum, kg * 4 + r, 64);

    float tl[4];
    #pragma unroll
    for (int n = 0; n < 4; ++n)
        tl[n] = vtail[((size_t)(b * 1024) + h * 64 + n * 16 + fr) * 32 + qt];

    #pragma unroll
    for (int n = 0; n < 4; ++n)
        #pragma unroll
        for (int r = 0; r < 4; ++r) {
            const int qrow = q0 + kg * 4 + r;
            ctx[baseQ + (size_t)qrow * D + n * 16 + fr] = f2bf((o[n][r] + tl[n]) / lq[r]);
        }
}

__global__ __launch_bounds__(256) void k_attn(
    const unsigned short* __restrict__ qp,
    const unsigned short* __restrict__ kp,
    const unsigned short* __restrict__ vt,
    const float* __restrict__ vtail,
    unsigned short* __restrict__ ctx)
{
    constexpr int S = 2048, D = 1024;
    const int p = blockIdx.x;    // pair index 0..15
    const int h = blockIdx.y;
    const int b = blockIdx.z;

    __shared__ alignas(16) unsigned char PlsB[4 * 16 * 128];   // per-wave P only

    const int tid  = threadIdx.x;
    const int lane = tid & 63, w = tid >> 6;
    const int fr   = lane & 15, kg = lane >> 4;
    unsigned char* PB = PlsB + w * 2048;

    const size_t baseQ = ((size_t)b * S) * D + (size_t)h * 64;
    const size_t baseV = ((size_t)b * D + (size_t)h * 64) * S;

    // pair (31-p, p): total key-tiles = (32-p) + (p+1) = 33, uniform
    attn_sweep(31 - p, qp, kp, vt, vtail, ctx, PB, baseQ, baseV, b, h, w, fr, kg);
    attn_sweep(p, qp, kp, vt, vtail, ctx, PB, baseQ, baseV, b, h, w, fr, kg);
}

// ---------------------------------------------------------------------------
extern "C" void kernel_launch(void* const* d_in, const int* in_sizes, int n_in,
                              void* d_out, int out_size, void* d_ws, size_t ws_size,
                              hipStream_t stream) {
    constexpr int B = 2, S = 2048, D = 1024;
    constexpr int M = B * S;                 // 4096
    constexpr size_t MD = (size_t)M * D;     // 4M elements

    const float* Q  = (const float*)d_in[0];
    const float* K  = (const float*)d_in[1];
    const float* V  = (const float*)d_in[2];
    const float* Wq = (const float*)d_in[4];
    const float* bq = (const float*)d_in[5];
    const float* Wk = (const float*)d_in[6];
    const float* bk = (const float*)d_in[7];
    const float* Wv = (const float*)d_in[8];
    const float* bv = (const float*)d_in[9];
    const float* Wo = (const float*)d_in[10];
    const float* bo = (const float*)d_in[11];

    // d_out (16 MiB, dead until final GEMM): qc (8 MiB) + kc (8 MiB)
    unsigned short* qc = (unsigned short*)d_out;
    unsigned short* kc = qc + MD;
    // d_ws (40 MiB): qb, kb, vtg, vc/ctx (8 MiB each) + Wto/Wtq/Wtk/Wtv (2 MiB each)
    char* ws = (char*)d_ws;
    unsigned short* qb  = (unsigned short*)(ws);
    unsigned short* kb  = (unsigned short*)(ws + (8u << 20));
    unsigned short* vtg = (unsigned short*)(ws + (16u << 20));
    unsigned short* vc  = (unsigned short*)(ws + (24u << 20));
    unsigned short* Wto = (unsigned short*)(ws + (32u << 20));
    unsigned short* Wtq = (unsigned short*)(ws + (34u << 20));
    unsigned short* Wtk = (unsigned short*)(ws + (36u << 20));
    unsigned short* Wtv = (unsigned short*)(ws + (38u << 20));
    unsigned short* ctx = vc;                       // aliases vc (dead by then)
    float* vtail        = (float*)Wtq;              // aliases Wtq (dead by then)

    dim3 blk(256);
    k_cvt<<<dim3(1024, 3), blk, 0, stream>>>(Q, K, V, qc, kc, vc);
    k_wt<<<dim3(16, 16, 4), blk, 0, stream>>>(Wq, Wk, Wv, Wo, Wtq, Wtk, Wtv, Wto);
    k_gemm_bf16<1><<<dim3(M / 128, D / 128, 3), blk, 0, stream>>>(
        qc, kc, vc, Wtq, Wtk, Wtv, bq, bk, bv, qb, kb, vtg);
    k_vtail<<<dim3((B * D) / 4), blk, 0, stream>>>(vtg, vtail);
    k_attn<<<dim3(16, 16, B), blk, 0, stream>>>(qb, kb, vtg, vtail, ctx);
    k_gemm_bf16<0><<<dim3(M / 128, D / 128, 1), blk, 0, stream>>>(
        ctx, ctx, ctx, Wto, Wto, Wto, bo, bo, bo, d_out, d_out, d_out);
}

// Round 12
// 134.389 us; speedup vs baseline: 1.7078x; 1.7078x over previous
//
#include <hip/hip_runtime.h>
#include <hip/hip_bf16.h>
#include <stdint.h>

#define DI __device__ __forceinline__

typedef __bf16 bf16x8 __attribute__((ext_vector_type(8)));
typedef float f32x4 __attribute__((ext_vector_type(4)));
typedef unsigned short ushortx8 __attribute__((ext_vector_type(8)));

// fp32 -> bf16 round-to-nearest-even (scalar path)
DI unsigned short f2bf(float f) {
    unsigned int u = __builtin_bit_cast(unsigned int, f);
    u += 0x7fffu + ((u >> 16) & 1u);
    return (unsigned short)(u >> 16);
}

// packed fp32x2 -> bf16x2 (1 VALU op). lo -> bits 0-15, hi -> bits 16-31.
DI unsigned int cvt_pk_bf16(float lo, float hi) {
    unsigned int r;
    asm("v_cvt_pk_bf16_f32 %0, %1, %2" : "=v"(r) : "v"(lo), "v"(hi));
    return r;
}

DI f32x4 mfma_16x16x32_bf16(bf16x8 a, bf16x8 b, f32x4 c) {
    return __builtin_amdgcn_mfma_f32_16x16x32_bf16(a, b, c, 0, 0, 0);
}

// async global->LDS, 16B per lane. LDS dest: wave-uniform base + lane*16.
DI void gload16(const unsigned short* g, unsigned short* l) {
    __builtin_amdgcn_global_load_lds(
        (const __attribute__((address_space(1))) void*)g,
        (__attribute__((address_space(3))) void*)l, 16, 0, 0);
}

// ---------------------------------------------------------------------------
// k_cvt: fp32 -> bf16 elementwise for Q, K, V (grid.y selects tensor).
// ---------------------------------------------------------------------------
__global__ __launch_bounds__(256) void k_cvt(
    const float* __restrict__ s0, const float* __restrict__ s1, const float* __restrict__ s2,
    unsigned short* __restrict__ d0, unsigned short* __restrict__ d1, unsigned short* __restrict__ d2)
{
    const int z = blockIdx.y;
    const float* s = z == 0 ? s0 : z == 1 ? s1 : s2;
    unsigned short* d = z == 0 ? d0 : z == 1 ? d1 : d2;
    const int i0 = blockIdx.x * 256 + threadIdx.x;
    #pragma unroll
    for (int it = 0; it < 4; ++it) {
        const int i = i0 + it * 262144;
        const float4 v = reinterpret_cast<const float4*>(s)[i];
        uint2 pk;
        pk.x = cvt_pk_bf16(v.x, v.y);
        pk.y = cvt_pk_bf16(v.z, v.w);
        reinterpret_cast<uint2*>(d)[i] = pk;
    }
}

// ---------------------------------------------------------------------------
// k_wt: W fp32 [1024][1024] -> Wt bf16 [n][k] (transposed), grid.z = 4 matrices.
// ---------------------------------------------------------------------------
__global__ __launch_bounds__(256) void k_wt(
    const float* __restrict__ w0, const float* __restrict__ w1,
    const float* __restrict__ w2, const float* __restrict__ w3,
    unsigned short* __restrict__ o0, unsigned short* __restrict__ o1,
    unsigned short* __restrict__ o2, unsigned short* __restrict__ o3)
{
    constexpr int N = 1024;
    const int z = blockIdx.z;
    const float* W = z == 0 ? w0 : z == 1 ? w1 : z == 2 ? w2 : w3;
    unsigned short* O = z == 0 ? o0 : z == 1 ? o1 : z == 2 ? o2 : o3;

    __shared__ unsigned short L[64 * 64];
    const int tid = threadIdx.x;
    const int k0 = blockIdx.x * 64, n0 = blockIdx.y * 64;

    const int r = tid >> 2, cbase = (tid & 3) * 16;
    #pragma unroll
    for (int i = 0; i < 4; ++i) {
        const int c = cbase + i * 4;
        const float4 v = *reinterpret_cast<const float4*>(&W[(size_t)(k0 + r) * N + n0 + c]);
        uint2 pk;
        pk.x = cvt_pk_bf16(v.x, v.y);
        pk.y = cvt_pk_bf16(v.z, v.w);
        const int byte = r * 128 + ((c * 2) ^ ((r & 7) << 4));
        *reinterpret_cast<uint2*>(reinterpret_cast<char*>(L) + byte) = pk;
    }
    __syncthreads();

    const int n = tid >> 2, kc = (tid & 3) * 16;
    ushortx8 v0, v1;
    #pragma unroll
    for (int j = 0; j < 8; ++j) {
        const int ka = kc + j, kb2 = kc + 8 + j;
        v0[j] = *reinterpret_cast<const unsigned short*>(
            reinterpret_cast<const char*>(L) + ka * 128 + ((n * 2) ^ ((ka & 7) << 4)));
        v1[j] = *reinterpret_cast<const unsigned short*>(
            reinterpret_cast<const char*>(L) + kb2 * 128 + ((n * 2) ^ ((kb2 & 7) << 4)));
    }
    unsigned short* op = &O[(size_t)(n0 + n) * N + k0 + kc];
    *reinterpret_cast<ushortx8*>(op) = v0;
    *reinterpret_cast<ushortx8*>(op + 8) = v1;
}

// ---------------------------------------------------------------------------
// bf16 GEMM, BK=64 (bisect candidate): half the barriers of BK=32, 32 MFMA
// per step. global_load_lds with PRE-SWIZZLED global source column
// ((l&7)^(l>>3)); fragment ds_reads XOR the same involution (^(fr&7)<<4).
// ---------------------------------------------------------------------------
template <int MODE>
__global__ __launch_bounds__(256) void k_gemm_bf16(
    const unsigned short* __restrict__ A0, const unsigned short* __restrict__ A1,
    const unsigned short* __restrict__ A2,
    const unsigned short* __restrict__ B0, const unsigned short* __restrict__ B1,
    const unsigned short* __restrict__ B2,
    const float* __restrict__ bias0, const float* __restrict__ bias1,
    const float* __restrict__ bias2,
    void* C0, void* C1, void* C2)
{
    constexpr int K = 1024, N = 1024;
    const int z = MODE ? blockIdx.z : 0;
    const unsigned short* A  = z == 0 ? A0 : z == 1 ? A1 : A2;
    const unsigned short* Bt = z == 0 ? B0 : z == 1 ? B1 : B2;
    const float* bias        = z == 0 ? bias0 : z == 1 ? bias1 : bias2;
    void* C                  = z == 0 ? C0 : z == 1 ? C1 : C2;

    __shared__ unsigned short As[128 * 64];   // 16 KB, [row][k] 128-B rows
    __shared__ unsigned short Bs[128 * 64];

    const int tid  = threadIdx.x;
    const int lane = tid & 63;
    const int w    = tid >> 6;
    const int wr   = w >> 1, wc = w & 1;
    const int fr   = lane & 15, kg = lane >> 4;
    const int m0   = blockIdx.x * 128, n0 = blockIdx.y * 128;

    // staging: chunk = 8 rows (1 KB); lane covers row c*8+(l>>3), swizzled col
    const int c0    = w * 4;
    const int srow8 = lane >> 3;                       // 0..7
    const int sswz  = ((lane & 7) ^ (lane >> 3)) * 8;  // pre-swizzled k-offset

    f32x4 acc[4][4] = {};

    for (int t = 0; t < K / 64; ++t) {
        const int k0 = t * 64;
        #pragma unroll
        for (int it = 0; it < 4; ++it) {
            const int c = c0 + it;
            const int row = c * 8 + srow8;
            gload16(&A[(size_t)(m0 + row) * K + k0 + sswz], &As[c * 512]);
            gload16(&Bt[(size_t)(n0 + row) * K + k0 + sswz], &Bs[c * 512]);
        }
        __syncthreads();

        const int rsw = (fr & 7) << 4;   // read-side XOR (byte)
        #pragma unroll
        for (int kh = 0; kh < 2; ++kh) {
            bf16x8 af[4], bfj[4];
            #pragma unroll
            for (int i = 0; i < 4; ++i)
                af[i] = *reinterpret_cast<const bf16x8*>(
                    reinterpret_cast<const char*>(As) +
                    (wr * 64 + i * 16 + fr) * 128 + ((kh * 64 + kg * 16) ^ rsw));
            #pragma unroll
            for (int j = 0; j < 4; ++j)
                bfj[j] = *reinterpret_cast<const bf16x8*>(
                    reinterpret_cast<const char*>(Bs) +
                    (wc * 64 + j * 16 + fr) * 128 + ((kh * 64 + kg * 16) ^ rsw));
            #pragma unroll
            for (int i = 0; i < 4; ++i)
                #pragma unroll
                for (int j = 0; j < 4; ++j)
                    acc[i][j] = mfma_16x16x32_bf16(af[i], bfj[j], acc[i][j]);
        }
        __syncthreads();
    }

    if (MODE == 1 && z == 2) {
        unsigned short* vt = reinterpret_cast<unsigned short*>(C);
        #pragma unroll
        for (int i = 0; i < 4; ++i) {
            const int m = m0 + wr * 64 + i * 16 + kg * 4;
            const int bb = m >> 11, s = m & 2047;
            #pragma unroll
            for (int j = 0; j < 4; ++j) {
                const int n = n0 + wc * 64 + j * 16 + fr;
                const float bv = bias[n];
                uint2 pk;
                pk.x = cvt_pk_bf16(acc[i][j][0] + bv, acc[i][j][1] + bv);
                pk.y = cvt_pk_bf16(acc[i][j][2] + bv, acc[i][j][3] + bv);
                *reinterpret_cast<uint2*>(&vt[((size_t)(bb * 1024 + n)) * 2048 + s]) = pk;
            }
        }
    } else if (MODE == 1) {
        const float sc = (z == 0) ? 0.125f : 1.0f;
        unsigned short* Cb = reinterpret_cast<unsigned short*>(C);
        #pragma unroll
        for (int i = 0; i < 4; ++i) {
            const int m = m0 + wr * 64 + i * 16 + kg * 4;
            #pragma unroll
            for (int j = 0; j < 4; ++j) {
                const int n = n0 + wc * 64 + j * 16 + fr;
                const float bv = bias[n];
                const unsigned int p0 = cvt_pk_bf16((acc[i][j][0] + bv) * sc, (acc[i][j][1] + bv) * sc);
                const unsigned int p1 = cvt_pk_bf16((acc[i][j][2] + bv) * sc, (acc[i][j][3] + bv) * sc);
                Cb[(size_t)(m + 0) * N + n] = (unsigned short)p0;
                Cb[(size_t)(m + 1) * N + n] = (unsigned short)(p0 >> 16);
                Cb[(size_t)(m + 2) * N + n] = (unsigned short)p1;
                Cb[(size_t)(m + 3) * N + n] = (unsigned short)(p1 >> 16);
            }
        }
    } else {
        float* Cf = reinterpret_cast<float*>(C);
        #pragma unroll
        for (int i = 0; i < 4; ++i) {
            const int m = m0 + wr * 64 + i * 16 + kg * 4;
            #pragma unroll
            for (int j = 0; j < 4; ++j) {
                const int n = n0 + wc * 64 + j * 16 + fr;
                const float bv = bias[n];
                #pragma unroll
                for (int r = 0; r < 4; ++r)
                    Cf[(size_t)(m + r) * N + n] = acc[i][j][r] + bv;
            }
        }
    }
}

// ---------------------------------------------------------------------------
// V tail suffix sums (unchanged).
// ---------------------------------------------------------------------------
__global__ __launch_bounds__(256) void k_vtail(
    const unsigned short* __restrict__ vt, float* __restrict__ vtail)
{
    const int row = blockIdx.x * 4 + (threadIdx.x >> 6);
    const int l = threadIdx.x & 63;
    const unsigned short* p = &vt[(size_t)row * 2048 + l * 32];
    float s = 0.f;
    #pragma unroll
    for (int i = 0; i < 4; ++i) {
        ushortx8 v = *reinterpret_cast<const ushortx8*>(&p[i * 8]);
        #pragma unroll
        for (int e = 0; e < 8; ++e)
            s += __builtin_bit_cast(float, (unsigned int)v[e] << 16);
    }
    #pragma unroll
    for (int off = 1; off < 64; off <<= 1) {
        const float t = __shfl_down(s, off, 64);
        s += (l + off < 64) ? t : 0.f;
    }
    float tv = __shfl(s, (2 * l + 2) & 63, 64);
    if (l == 31) tv = 0.f;
    if (l < 32) vtail[(size_t)row * 32 + l] = tv;
}

// ---------------------------------------------------------------------------
// Attention: EXACT round-8 version (last known good). Causal pair balancing,
// dbuf swizzled LDS, 1-deep register prefetch, swapped QK^T + V-tail.
// ---------------------------------------------------------------------------
template <bool MASK>
DI void attn_tile(const unsigned char* KsB, const unsigned char* VtsB,
                  unsigned char* PB, bf16x8 qf0, bf16x8 qf1,
                  f32x4 (&o)[4], float& lsum, int w, int fr, int kg)
{
    const int sw = (fr & 7) << 4;
    #pragma unroll
    for (int j = 0; j < 4; ++j) {
        const int row = j * 16 + fr;
        const bf16x8 kf0 = *reinterpret_cast<const bf16x8*>(KsB + row * 128 + ((kg * 16) ^ sw));
        const bf16x8 kf1 = *reinterpret_cast<const bf16x8*>(KsB + row * 128 + ((64 + kg * 16) ^ sw));
        f32x4 s = {0.f, 0.f, 0.f, 0.f};
        s = mfma_16x16x32_bf16(kf0, qf0, s);   // swapped: A=K rows (keys), B=Q
        s = mfma_16x16x32_bf16(kf1, qf1, s);
        float p[4];
        #pragma unroll
        for (int r = 0; r < 4; ++r) {
            float e = __expf(s[r]);
            if (MASK && (j * 16 + kg * 4 + r > w * 16 + fr)) e = 1.0f;  // exp(-1e-8)==1.0f
            p[r] = e;
            lsum += e;
        }
        uint2 pk;
        pk.x = cvt_pk_bf16(p[0], p[1]);
        pk.y = cvt_pk_bf16(p[2], p[3]);
        *reinterpret_cast<uint2*>(PB + fr * 128 + ((j * 32 + kg * 8) ^ sw)) = pk;
    }
    #pragma unroll
    for (int kk = 0; kk < 2; ++kk) {
        const bf16x8 pf = *reinterpret_cast<const bf16x8*>(PB + fr * 128 + ((kk * 64 + kg * 16) ^ sw));
        #pragma unroll
        for (int n = 0; n < 4; ++n) {
            const int vrow = n * 16 + fr;
            const bf16x8 vf = *reinterpret_cast<const bf16x8*>(VtsB + vrow * 128 + ((kk * 64 + kg * 16) ^ sw));
            o[n] = mfma_16x16x32_bf16(pf, vf, o[n]);
        }
    }
}

DI void attn_sweep(int qt,
                   const unsigned short* __restrict__ qp,
                   const unsigned short* __restrict__ kp,
                   const unsigned short* __restrict__ vt,
                   const float* __restrict__ vtail,
                   unsigned short* __restrict__ ctx,
                   unsigned char (*KsB)[64 * 128], unsigned char (*VtsB)[64 * 128],
                   unsigned char* PB, size_t baseQ, size_t baseV, int b, int h,
                   int w, int fr, int kg, int sr, int sc8, int wb0, int wb1)
{
    constexpr int S = 2048, D = 1024;
    const int q0 = qt * 64 + w * 16;

    bf16x8 qf0, qf1;
    {
        const size_t roff = baseQ + (size_t)(q0 + fr) * D;
        qf0 = *reinterpret_cast<const bf16x8*>(&qp[roff + kg * 8]);
        qf1 = *reinterpret_cast<const bf16x8*>(&qp[roff + 32 + kg * 8]);
    }

    f32x4 o[4] = {};
    float lsum = 0.f;
    const int NT = qt + 1;

    // prologue: stage tile 0 into buffer 0
    {
        const ushortx8 kr0 = *reinterpret_cast<const ushortx8*>(&kp[baseQ + (size_t)sr * D + sc8]);
        const ushortx8 kr1 = *reinterpret_cast<const ushortx8*>(&kp[baseQ + (size_t)(sr + 32) * D + sc8]);
        const ushortx8 vr0 = *reinterpret_cast<const ushortx8*>(&vt[baseV + (size_t)sr * S + sc8]);
        const ushortx8 vr1 = *reinterpret_cast<const ushortx8*>(&vt[baseV + (size_t)(sr + 32) * S + sc8]);
        *reinterpret_cast<ushortx8*>(KsB[0] + wb0)  = kr0;
        *reinterpret_cast<ushortx8*>(KsB[0] + wb1)  = kr1;
        *reinterpret_cast<ushortx8*>(VtsB[0] + wb0) = vr0;
        *reinterpret_cast<ushortx8*>(VtsB[0] + wb1) = vr1;
    }
    __syncthreads();

    for (int t = 0; t < NT; ++t) {
        const int cur = t & 1;
        const bool more = (t + 1 < NT);
        ushortx8 nk0, nk1, nv0, nv1;
        if (more) {   // T14: issue next-tile loads before compute
            const int kt1 = (t + 1) * 64;
            nk0 = *reinterpret_cast<const ushortx8*>(&kp[baseQ + (size_t)(kt1 + sr) * D + sc8]);
            nk1 = *reinterpret_cast<const ushortx8*>(&kp[baseQ + (size_t)(kt1 + sr + 32) * D + sc8]);
            nv0 = *reinterpret_cast<const ushortx8*>(&vt[baseV + (size_t)sr * S + kt1 + sc8]);
            nv1 = *reinterpret_cast<const ushortx8*>(&vt[baseV + (size_t)(sr + 32) * S + kt1 + sc8]);
        }
        if (more)
            attn_tile<false>(KsB[cur], VtsB[cur], PB, qf0, qf1, o, lsum, w, fr, kg);
        else
            attn_tile<true>(KsB[cur], VtsB[cur], PB, qf0, qf1, o, lsum, w, fr, kg);
        if (more) {   // write next tile into the other buffer (no extra barrier)
            const int nxt = cur ^ 1;
            *reinterpret_cast<ushortx8*>(KsB[nxt] + wb0)  = nk0;
            *reinterpret_cast<ushortx8*>(KsB[nxt] + wb1)  = nk1;
            *reinterpret_cast<ushortx8*>(VtsB[nxt] + wb0) = nv0;
            *reinterpret_cast<ushortx8*>(VtsB[nxt] + wb1) = nv1;
        }
        __syncthreads();
    }

    // full row sums: combine the 4 key-groups, add analytic tail count
    lsum += __shfl_xor(lsum, 16, 64);
    lsum += __shfl_xor(lsum, 32, 64);
    lsum += (float)(S - (qt + 1) * 64);

    float lq[4];
    #pragma unroll
    for (int r = 0; r < 4; ++r) lq[r] = __shfl(lsum, kg * 4 + r, 64);

    float tl[4];
    #pragma unroll
    for (int n = 0; n < 4; ++n)
        tl[n] = vtail[((size_t)(b * 1024) + h * 64 + n * 16 + fr) * 32 + qt];

    #pragma unroll
    for (int n = 0; n < 4; ++n)
        #pragma unroll
        for (int r = 0; r < 4; ++r) {
            const int qrow = q0 + kg * 4 + r;
            ctx[baseQ + (size_t)qrow * D + n * 16 + fr] = f2bf((o[n][r] + tl[n]) / lq[r]);
        }
}

__global__ __launch_bounds__(256, 2) void k_attn(
    const unsigned short* __restrict__ qp,
    const unsigned short* __restrict__ kp,
    const unsigned short* __restrict__ vt,
    const float* __restrict__ vtail,
    unsigned short* __restrict__ ctx)
{
    constexpr int S = 2048, D = 1024;
    const int p = blockIdx.x;    // pair index 0..15
    const int h = blockIdx.y;
    const int b = blockIdx.z;

    __shared__ alignas(16) unsigned char KsB[2][64 * 128];     // dbuf K, swizzled
    __shared__ alignas(16) unsigned char VtsB[2][64 * 128];    // dbuf V, swizzled
    __shared__ alignas(16) unsigned char PlsB[4 * 16 * 128];   // per-wave P

    const int tid  = threadIdx.x;
    const int lane = tid & 63, w = tid >> 6;
    const int fr   = lane & 15, kg = lane >> 4;
    unsigned char* PB = PlsB + w * 2048;

    const size_t baseQ = ((size_t)b * S) * D + (size_t)h * 64;
    const size_t baseV = ((size_t)b * D + (size_t)h * 64) * S;

    const int sr  = tid >> 3;          // staging row 0..31
    const int sc8 = (tid & 7) * 8;     // element offset (8 bf16)
    const int wb0 = sr * 128 + (((tid & 7) * 16) ^ ((sr & 7) << 4));
    const int wb1 = (sr + 32) * 128 + (((tid & 7) * 16) ^ (((sr + 32) & 7) << 4));

    // pair (31-p, p): total key-tiles = (32-p) + (p+1) = 33, uniform
    attn_sweep(31 - p, qp, kp, vt, vtail, ctx, KsB, VtsB, PB,
               baseQ, baseV, b, h, w, fr, kg, sr, sc8, wb0, wb1);
    attn_sweep(p, qp, kp, vt, vtail, ctx, KsB, VtsB, PB,
               baseQ, baseV, b, h, w, fr, kg, sr, sc8, wb0, wb1);
}

// ---------------------------------------------------------------------------
extern "C" void kernel_launch(void* const* d_in, const int* in_sizes, int n_in,
                              void* d_out, int out_size, void* d_ws, size_t ws_size,
                              hipStream_t stream) {
    constexpr int B = 2, S = 2048, D = 1024;
    constexpr int M = B * S;                 // 4096
    constexpr size_t MD = (size_t)M * D;     // 4M elements

    const float* Q  = (const float*)d_in[0];
    const float* K  = (const float*)d_in[1];
    const float* V  = (const float*)d_in[2];
    const float* Wq = (const float*)d_in[4];
    const float* bq = (const float*)d_in[5];
    const float* Wk = (const float*)d_in[6];
    const float* bk = (const float*)d_in[7];
    const float* Wv = (const float*)d_in[8];
    const float* bv = (const float*)d_in[9];
    const float* Wo = (const float*)d_in[10];
    const float* bo = (const float*)d_in[11];

    // d_out (16 MiB, dead until final GEMM): qc (8 MiB) + kc (8 MiB)
    unsigned short* qc = (unsigned short*)d_out;
    unsigned short* kc = qc + MD;
    // d_ws (40 MiB): qb, kb, vtg, vc/ctx (8 MiB each) + Wto/Wtq/Wtk/Wtv (2 MiB each)
    char* ws = (char*)d_ws;
    unsigned short* qb  = (unsigned short*)(ws);
    unsigned short* kb  = (unsigned short*)(ws + (8u << 20));
    unsigned short* vtg = (unsigned short*)(ws + (16u << 20));
    unsigned short* vc  = (unsigned short*)(ws + (24u << 20));
    unsigned short* Wto = (unsigned short*)(ws + (32u << 20));
    unsigned short* Wtq = (unsigned short*)(ws + (34u << 20));
    unsigned short* Wtk = (unsigned short*)(ws + (36u << 20));
    unsigned short* Wtv = (unsigned short*)(ws + (38u << 20));
    unsigned short* ctx = vc;                       // aliases vc (dead by then)
    float* vtail        = (float*)Wtq;              // aliases Wtq (dead by then)

    dim3 blk(256);
    k_cvt<<<dim3(1024, 3), blk, 0, stream>>>(Q, K, V, qc, kc, vc);
    k_wt<<<dim3(16, 16, 4), blk, 0, stream>>>(Wq, Wk, Wv, Wo, Wtq, Wtk, Wtv, Wto);
    k_gemm_bf16<1><<<dim3(M / 128, D / 128, 3), blk, 0, stream>>>(
        qc, kc, vc, Wtq, Wtk, Wtv, bq, bk, bv, qb, kb, vtg);
    k_vtail<<<dim3((B * D) / 4), blk, 0, stream>>>(vtg, vtail);
    k_attn<<<dim3(16, 16, B), blk, 0, stream>>>(qb, kb, vtg, vtail, ctx);
    k_gemm_bf16<0><<<dim3(M / 128, D / 128, 1), blk, 0, stream>>>(
        ctx, ctx, ctx, Wto, Wto, Wto, bo, bo, bo, d_out, d_out, d_out);
}

// Round 13
// 125.152 us; speedup vs baseline: 1.8339x; 1.0738x over previous
//
#include <hip/hip_runtime.h>
#include <hip/hip_bf16.h>
#include <stdint.h>

#define DI __device__ __forceinline__

typedef __bf16 bf16x8 __attribute__((ext_vector_type(8)));
typedef float f32x4 __attribute__((ext_vector_type(4)));
typedef unsigned short ushortx8 __attribute__((ext_vector_type(8)));

// fp32 -> bf16 round-to-nearest-even (scalar path)
DI unsigned short f2bf(float f) {
    unsigned int u = __builtin_bit_cast(unsigned int, f);
    u += 0x7fffu + ((u >> 16) & 1u);
    return (unsigned short)(u >> 16);
}

// packed fp32x2 -> bf16x2 (1 VALU op). lo -> bits 0-15, hi -> bits 16-31.
DI unsigned int cvt_pk_bf16(float lo, float hi) {
    unsigned int r;
    asm("v_cvt_pk_bf16_f32 %0, %1, %2" : "=v"(r) : "v"(lo), "v"(hi));
    return r;
}

DI f32x4 mfma_16x16x32_bf16(bf16x8 a, bf16x8 b, f32x4 c) {
    return __builtin_amdgcn_mfma_f32_16x16x32_bf16(a, b, c, 0, 0, 0);
}

// async global->LDS, 16B per lane. LDS dest: wave-uniform base + lane*16.
DI void gload16(const unsigned short* g, unsigned short* l) {
    __builtin_amdgcn_global_load_lds(
        (const __attribute__((address_space(1))) void*)g,
        (__attribute__((address_space(3))) void*)l, 16, 0, 0);
}

// ---------------------------------------------------------------------------
// k_cvt: fp32 -> bf16 elementwise for Q, K, V (grid.y selects tensor).
// ---------------------------------------------------------------------------
__global__ __launch_bounds__(256) void k_cvt(
    const float* __restrict__ s0, const float* __restrict__ s1, const float* __restrict__ s2,
    unsigned short* __restrict__ d0, unsigned short* __restrict__ d1, unsigned short* __restrict__ d2)
{
    const int z = blockIdx.y;
    const float* s = z == 0 ? s0 : z == 1 ? s1 : s2;
    unsigned short* d = z == 0 ? d0 : z == 1 ? d1 : d2;
    const int i0 = blockIdx.x * 256 + threadIdx.x;
    #pragma unroll
    for (int it = 0; it < 4; ++it) {
        const int i = i0 + it * 262144;
        const float4 v = reinterpret_cast<const float4*>(s)[i];
        uint2 pk;
        pk.x = cvt_pk_bf16(v.x, v.y);
        pk.y = cvt_pk_bf16(v.z, v.w);
        reinterpret_cast<uint2*>(d)[i] = pk;
    }
}

// ---------------------------------------------------------------------------
// k_wt: W fp32 [1024][1024] -> Wt bf16 [n][k] (transposed), grid.z = 4 matrices.
// ---------------------------------------------------------------------------
__global__ __launch_bounds__(256) void k_wt(
    const float* __restrict__ w0, const float* __restrict__ w1,
    const float* __restrict__ w2, const float* __restrict__ w3,
    unsigned short* __restrict__ o0, unsigned short* __restrict__ o1,
    unsigned short* __restrict__ o2, unsigned short* __restrict__ o3)
{
    constexpr int N = 1024;
    const int z = blockIdx.z;
    const float* W = z == 0 ? w0 : z == 1 ? w1 : z == 2 ? w2 : w3;
    unsigned short* O = z == 0 ? o0 : z == 1 ? o1 : z == 2 ? o2 : o3;

    __shared__ unsigned short L[64 * 64];
    const int tid = threadIdx.x;
    const int k0 = blockIdx.x * 64, n0 = blockIdx.y * 64;

    const int r = tid >> 2, cbase = (tid & 3) * 16;
    #pragma unroll
    for (int i = 0; i < 4; ++i) {
        const int c = cbase + i * 4;
        const float4 v = *reinterpret_cast<const float4*>(&W[(size_t)(k0 + r) * N + n0 + c]);
        uint2 pk;
        pk.x = cvt_pk_bf16(v.x, v.y);
        pk.y = cvt_pk_bf16(v.z, v.w);
        const int byte = r * 128 + ((c * 2) ^ ((r & 7) << 4));
        *reinterpret_cast<uint2*>(reinterpret_cast<char*>(L) + byte) = pk;
    }
    __syncthreads();

    const int n = tid >> 2, kc = (tid & 3) * 16;
    ushortx8 v0, v1;
    #pragma unroll
    for (int j = 0; j < 8; ++j) {
        const int ka = kc + j, kb2 = kc + 8 + j;
        v0[j] = *reinterpret_cast<const unsigned short*>(
            reinterpret_cast<const char*>(L) + ka * 128 + ((n * 2) ^ ((ka & 7) << 4)));
        v1[j] = *reinterpret_cast<const unsigned short*>(
            reinterpret_cast<const char*>(L) + kb2 * 128 + ((n * 2) ^ ((kb2 & 7) << 4)));
    }
    unsigned short* op = &O[(size_t)(n0 + n) * N + k0 + kc];
    *reinterpret_cast<ushortx8*>(op) = v0;
    *reinterpret_cast<ushortx8*>(op + 8) = v1;
}

// ---------------------------------------------------------------------------
// bf16 GEMM, BK=64 (proven round-12): 16 barriers, 32 MFMA/step, both-sides
// swizzle (pre-swizzled global source + XOR'd ds_read).
// ---------------------------------------------------------------------------
template <int MODE>
__global__ __launch_bounds__(256) void k_gemm_bf16(
    const unsigned short* __restrict__ A0, const unsigned short* __restrict__ A1,
    const unsigned short* __restrict__ A2,
    const unsigned short* __restrict__ B0, const unsigned short* __restrict__ B1,
    const unsigned short* __restrict__ B2,
    const float* __restrict__ bias0, const float* __restrict__ bias1,
    const float* __restrict__ bias2,
    void* C0, void* C1, void* C2)
{
    constexpr int K = 1024, N = 1024;
    const int z = MODE ? blockIdx.z : 0;
    const unsigned short* A  = z == 0 ? A0 : z == 1 ? A1 : A2;
    const unsigned short* Bt = z == 0 ? B0 : z == 1 ? B1 : B2;
    const float* bias        = z == 0 ? bias0 : z == 1 ? bias1 : bias2;
    void* C                  = z == 0 ? C0 : z == 1 ? C1 : C2;

    __shared__ unsigned short As[128 * 64];   // 16 KB, [row][k] 128-B rows
    __shared__ unsigned short Bs[128 * 64];

    const int tid  = threadIdx.x;
    const int lane = tid & 63;
    const int w    = tid >> 6;
    const int wr   = w >> 1, wc = w & 1;
    const int fr   = lane & 15, kg = lane >> 4;
    const int m0   = blockIdx.x * 128, n0 = blockIdx.y * 128;

    // staging: chunk = 8 rows (1 KB); lane covers row c*8+(l>>3), swizzled col
    const int c0    = w * 4;
    const int srow8 = lane >> 3;                       // 0..7
    const int sswz  = ((lane & 7) ^ (lane >> 3)) * 8;  // pre-swizzled k-offset

    f32x4 acc[4][4] = {};

    for (int t = 0; t < K / 64; ++t) {
        const int k0 = t * 64;
        #pragma unroll
        for (int it = 0; it < 4; ++it) {
            const int c = c0 + it;
            const int row = c * 8 + srow8;
            gload16(&A[(size_t)(m0 + row) * K + k0 + sswz], &As[c * 512]);
            gload16(&Bt[(size_t)(n0 + row) * K + k0 + sswz], &Bs[c * 512]);
        }
        __syncthreads();

        const int rsw = (fr & 7) << 4;   // read-side XOR (byte)
        #pragma unroll
        for (int kh = 0; kh < 2; ++kh) {
            bf16x8 af[4], bfj[4];
            #pragma unroll
            for (int i = 0; i < 4; ++i)
                af[i] = *reinterpret_cast<const bf16x8*>(
                    reinterpret_cast<const char*>(As) +
                    (wr * 64 + i * 16 + fr) * 128 + ((kh * 64 + kg * 16) ^ rsw));
            #pragma unroll
            for (int j = 0; j < 4; ++j)
                bfj[j] = *reinterpret_cast<const bf16x8*>(
                    reinterpret_cast<const char*>(Bs) +
                    (wc * 64 + j * 16 + fr) * 128 + ((kh * 64 + kg * 16) ^ rsw));
            #pragma unroll
            for (int i = 0; i < 4; ++i)
                #pragma unroll
                for (int j = 0; j < 4; ++j)
                    acc[i][j] = mfma_16x16x32_bf16(af[i], bfj[j], acc[i][j]);
        }
        __syncthreads();
    }

    if (MODE == 1 && z == 2) {
        unsigned short* vt = reinterpret_cast<unsigned short*>(C);
        #pragma unroll
        for (int i = 0; i < 4; ++i) {
            const int m = m0 + wr * 64 + i * 16 + kg * 4;
            const int bb = m >> 11, s = m & 2047;
            #pragma unroll
            for (int j = 0; j < 4; ++j) {
                const int n = n0 + wc * 64 + j * 16 + fr;
                const float bv = bias[n];
                uint2 pk;
                pk.x = cvt_pk_bf16(acc[i][j][0] + bv, acc[i][j][1] + bv);
                pk.y = cvt_pk_bf16(acc[i][j][2] + bv, acc[i][j][3] + bv);
                *reinterpret_cast<uint2*>(&vt[((size_t)(bb * 1024 + n)) * 2048 + s]) = pk;
            }
        }
    } else if (MODE == 1) {
        const float sc = (z == 0) ? 0.125f : 1.0f;
        unsigned short* Cb = reinterpret_cast<unsigned short*>(C);
        #pragma unroll
        for (int i = 0; i < 4; ++i) {
            const int m = m0 + wr * 64 + i * 16 + kg * 4;
            #pragma unroll
            for (int j = 0; j < 4; ++j) {
                const int n = n0 + wc * 64 + j * 16 + fr;
                const float bv = bias[n];
                const unsigned int p0 = cvt_pk_bf16((acc[i][j][0] + bv) * sc, (acc[i][j][1] + bv) * sc);
                const unsigned int p1 = cvt_pk_bf16((acc[i][j][2] + bv) * sc, (acc[i][j][3] + bv) * sc);
                Cb[(size_t)(m + 0) * N + n] = (unsigned short)p0;
                Cb[(size_t)(m + 1) * N + n] = (unsigned short)(p0 >> 16);
                Cb[(size_t)(m + 2) * N + n] = (unsigned short)p1;
                Cb[(size_t)(m + 3) * N + n] = (unsigned short)(p1 >> 16);
            }
        }
    } else {
        float* Cf = reinterpret_cast<float*>(C);
        #pragma unroll
        for (int i = 0; i < 4; ++i) {
            const int m = m0 + wr * 64 + i * 16 + kg * 4;
            #pragma unroll
            for (int j = 0; j < 4; ++j) {
                const int n = n0 + wc * 64 + j * 16 + fr;
                const float bv = bias[n];
                #pragma unroll
                for (int r = 0; r < 4; ++r)
                    Cf[(size_t)(m + r) * N + n] = acc[i][j][r] + bv;
            }
        }
    }
}

// ---------------------------------------------------------------------------
// V tail suffix sums (unchanged).
// ---------------------------------------------------------------------------
__global__ __launch_bounds__(256) void k_vtail(
    const unsigned short* __restrict__ vt, float* __restrict__ vtail)
{
    const int row = blockIdx.x * 4 + (threadIdx.x >> 6);
    const int l = threadIdx.x & 63;
    const unsigned short* p = &vt[(size_t)row * 2048 + l * 32];
    float s = 0.f;
    #pragma unroll
    for (int i = 0; i < 4; ++i) {
        ushortx8 v = *reinterpret_cast<const ushortx8*>(&p[i * 8]);
        #pragma unroll
        for (int e = 0; e < 8; ++e)
            s += __builtin_bit_cast(float, (unsigned int)v[e] << 16);
    }
    #pragma unroll
    for (int off = 1; off < 64; off <<= 1) {
        const float t = __shfl_down(s, off, 64);
        s += (l + off < 64) ? t : 0.f;
    }
    float tv = __shfl(s, (2 * l + 2) & 63, 64);
    if (l == 31) tv = 0.f;
    if (l < 32) vtail[(size_t)row * 32 + l] = tv;
}

// ---------------------------------------------------------------------------
// Attention (round-12 proven body) + T1 chunked XCD swizzle: 1D grid of 512;
// G = (L%8)*64 + L/8 puts 64 consecutive logical blocks (= 4 complete (h,b)
// panel groups, 2 MB K+V) on ONE XCD -> panels are fetched into a single L2
// and hit by all 16 sharing blocks instead of being replicated across 8 L2s.
// ---------------------------------------------------------------------------
template <bool MASK>
DI void attn_tile(const unsigned char* KsB, const unsigned char* VtsB,
                  unsigned char* PB, bf16x8 qf0, bf16x8 qf1,
                  f32x4 (&o)[4], float& lsum, int w, int fr, int kg)
{
    const int sw = (fr & 7) << 4;
    #pragma unroll
    for (int j = 0; j < 4; ++j) {
        const int row = j * 16 + fr;
        const bf16x8 kf0 = *reinterpret_cast<const bf16x8*>(KsB + row * 128 + ((kg * 16) ^ sw));
        const bf16x8 kf1 = *reinterpret_cast<const bf16x8*>(KsB + row * 128 + ((64 + kg * 16) ^ sw));
        f32x4 s = {0.f, 0.f, 0.f, 0.f};
        s = mfma_16x16x32_bf16(kf0, qf0, s);   // swapped: A=K rows (keys), B=Q
        s = mfma_16x16x32_bf16(kf1, qf1, s);
        float p[4];
        #pragma unroll
        for (int r = 0; r < 4; ++r) {
            float e = __expf(s[r]);
            if (MASK && (j * 16 + kg * 4 + r > w * 16 + fr)) e = 1.0f;  // exp(-1e-8)==1.0f
            p[r] = e;
            lsum += e;
        }
        uint2 pk;
        pk.x = cvt_pk_bf16(p[0], p[1]);
        pk.y = cvt_pk_bf16(p[2], p[3]);
        *reinterpret_cast<uint2*>(PB + fr * 128 + ((j * 32 + kg * 8) ^ sw)) = pk;
    }
    #pragma unroll
    for (int kk = 0; kk < 2; ++kk) {
        const bf16x8 pf = *reinterpret_cast<const bf16x8*>(PB + fr * 128 + ((kk * 64 + kg * 16) ^ sw));
        #pragma unroll
        for (int n = 0; n < 4; ++n) {
            const int vrow = n * 16 + fr;
            const bf16x8 vf = *reinterpret_cast<const bf16x8*>(VtsB + vrow * 128 + ((kk * 64 + kg * 16) ^ sw));
            o[n] = mfma_16x16x32_bf16(pf, vf, o[n]);
        }
    }
}

DI void attn_sweep(int qt,
                   const unsigned short* __restrict__ qp,
                   const unsigned short* __restrict__ kp,
                   const unsigned short* __restrict__ vt,
                   const float* __restrict__ vtail,
                   unsigned short* __restrict__ ctx,
                   unsigned char (*KsB)[64 * 128], unsigned char (*VtsB)[64 * 128],
                   unsigned char* PB, size_t baseQ, size_t baseV, int b, int h,
                   int w, int fr, int kg, int sr, int sc8, int wb0, int wb1)
{
    constexpr int S = 2048, D = 1024;
    const int q0 = qt * 64 + w * 16;

    bf16x8 qf0, qf1;
    {
        const size_t roff = baseQ + (size_t)(q0 + fr) * D;
        qf0 = *reinterpret_cast<const bf16x8*>(&qp[roff + kg * 8]);
        qf1 = *reinterpret_cast<const bf16x8*>(&qp[roff + 32 + kg * 8]);
    }

    f32x4 o[4] = {};
    float lsum = 0.f;
    const int NT = qt + 1;

    // prologue: stage tile 0 into buffer 0
    {
        const ushortx8 kr0 = *reinterpret_cast<const ushortx8*>(&kp[baseQ + (size_t)sr * D + sc8]);
        const ushortx8 kr1 = *reinterpret_cast<const ushortx8*>(&kp[baseQ + (size_t)(sr + 32) * D + sc8]);
        const ushortx8 vr0 = *reinterpret_cast<const ushortx8*>(&vt[baseV + (size_t)sr * S + sc8]);
        const ushortx8 vr1 = *reinterpret_cast<const ushortx8*>(&vt[baseV + (size_t)(sr + 32) * S + sc8]);
        *reinterpret_cast<ushortx8*>(KsB[0] + wb0)  = kr0;
        *reinterpret_cast<ushortx8*>(KsB[0] + wb1)  = kr1;
        *reinterpret_cast<ushortx8*>(VtsB[0] + wb0) = vr0;
        *reinterpret_cast<ushortx8*>(VtsB[0] + wb1) = vr1;
    }
    __syncthreads();

    for (int t = 0; t < NT; ++t) {
        const int cur = t & 1;
        const bool more = (t + 1 < NT);
        ushortx8 nk0, nk1, nv0, nv1;
        if (more) {   // T14: issue next-tile loads before compute
            const int kt1 = (t + 1) * 64;
            nk0 = *reinterpret_cast<const ushortx8*>(&kp[baseQ + (size_t)(kt1 + sr) * D + sc8]);
            nk1 = *reinterpret_cast<const ushortx8*>(&kp[baseQ + (size_t)(kt1 + sr + 32) * D + sc8]);
            nv0 = *reinterpret_cast<const ushortx8*>(&vt[baseV + (size_t)sr * S + kt1 + sc8]);
            nv1 = *reinterpret_cast<const ushortx8*>(&vt[baseV + (size_t)(sr + 32) * S + kt1 + sc8]);
        }
        if (more)
            attn_tile<false>(KsB[cur], VtsB[cur], PB, qf0, qf1, o, lsum, w, fr, kg);
        else
            attn_tile<true>(KsB[cur], VtsB[cur], PB, qf0, qf1, o, lsum, w, fr, kg);
        if (more) {   // write next tile into the other buffer (no extra barrier)
            const int nxt = cur ^ 1;
            *reinterpret_cast<ushortx8*>(KsB[nxt] + wb0)  = nk0;
            *reinterpret_cast<ushortx8*>(KsB[nxt] + wb1)  = nk1;
            *reinterpret_cast<ushortx8*>(VtsB[nxt] + wb0) = nv0;
            *reinterpret_cast<ushortx8*>(VtsB[nxt] + wb1) = nv1;
        }
        __syncthreads();
    }

    // full row sums: combine the 4 key-groups, add analytic tail count
    lsum += __shfl_xor(lsum, 16, 64);
    lsum += __shfl_xor(lsum, 32, 64);
    lsum += (float)(S - (qt + 1) * 64);

    float lq[4];
    #pragma unroll
    for (int r = 0; r < 4; ++r) lq[r] = __shfl(lsum, kg * 4 + r, 64);

    float tl[4];
    #pragma unroll
    for (int n = 0; n < 4; ++n)
        tl[n] = vtail[((size_t)(b * 1024) + h * 64 + n * 16 + fr) * 32 + qt];

    #pragma unroll
    for (int n = 0; n < 4; ++n)
        #pragma unroll
        for (int r = 0; r < 4; ++r) {
            const int qrow = q0 + kg * 4 + r;
            ctx[baseQ + (size_t)qrow * D + n * 16 + fr] = f2bf((o[n][r] + tl[n]) / lq[r]);
        }
}

__global__ __launch_bounds__(256, 2) void k_attn(
    const unsigned short* __restrict__ qp,
    const unsigned short* __restrict__ kp,
    const unsigned short* __restrict__ vt,
    const float* __restrict__ vtail,
    unsigned short* __restrict__ ctx)
{
    constexpr int S = 2048, D = 1024;
    // T1 chunked XCD swizzle: HW assigns linear block L to XCD ~L%8.
    // G = (L%8)*64 + L/8 makes each XCD's 64 resident blocks a contiguous
    // logical chunk = 4 complete (h,b) panel groups (bijective: 512 = 8*64).
    const int L = blockIdx.x;
    const int G = (L & 7) * 64 + (L >> 3);
    const int p = G & 15;            // pair index 0..15
    const int h = (G >> 4) & 15;     // head
    const int b = G >> 8;            // batch

    __shared__ alignas(16) unsigned char KsB[2][64 * 128];     // dbuf K, swizzled
    __shared__ alignas(16) unsigned char VtsB[2][64 * 128];    // dbuf V, swizzled
    __shared__ alignas(16) unsigned char PlsB[4 * 16 * 128];   // per-wave P

    const int tid  = threadIdx.x;
    const int lane = tid & 63, w = tid >> 6;
    const int fr   = lane & 15, kg = lane >> 4;
    unsigned char* PB = PlsB + w * 2048;

    const size_t baseQ = ((size_t)b * S) * D + (size_t)h * 64;
    const size_t baseV = ((size_t)b * D + (size_t)h * 64) * S;

    const int sr  = tid >> 3;          // staging row 0..31
    const int sc8 = (tid & 7) * 8;     // element offset (8 bf16)
    const int wb0 = sr * 128 + (((tid & 7) * 16) ^ ((sr & 7) << 4));
    const int wb1 = (sr + 32) * 128 + (((tid & 7) * 16) ^ (((sr + 32) & 7) << 4));

    // pair (31-p, p): total key-tiles = (32-p) + (p+1) = 33, uniform
    attn_sweep(31 - p, qp, kp, vt, vtail, ctx, KsB, VtsB, PB,
               baseQ, baseV, b, h, w, fr, kg, sr, sc8, wb0, wb1);
    attn_sweep(p, qp, kp, vt, vtail, ctx, KsB, VtsB, PB,
               baseQ, baseV, b, h, w, fr, kg, sr, sc8, wb0, wb1);
}

// ---------------------------------------------------------------------------
extern "C" void kernel_launch(void* const* d_in, const int* in_sizes, int n_in,
                              void* d_out, int out_size, void* d_ws, size_t ws_size,
                              hipStream_t stream) {
    constexpr int B = 2, S = 2048, D = 1024;
    constexpr int M = B * S;                 // 4096
    constexpr size_t MD = (size_t)M * D;     // 4M elements

    const float* Q  = (const float*)d_in[0];
    const float* K  = (const float*)d_in[1];
    const float* V  = (const float*)d_in[2];
    const float* Wq = (const float*)d_in[4];
    const float* bq = (const float*)d_in[5];
    const float* Wk = (const float*)d_in[6];
    const float* bk = (const float*)d_in[7];
    const float* Wv = (const float*)d_in[8];
    const float* bv = (const float*)d_in[9];
    const float* Wo = (const float*)d_in[10];
    const float* bo = (const float*)d_in[11];

    // d_out (16 MiB, dead until final GEMM): qc (8 MiB) + kc (8 MiB)
    unsigned short* qc = (unsigned short*)d_out;
    unsigned short* kc = qc + MD;
    // d_ws (40 MiB): qb, kb, vtg, vc/ctx (8 MiB each) + Wto/Wtq/Wtk/Wtv (2 MiB each)
    char* ws = (char*)d_ws;
    unsigned short* qb  = (unsigned short*)(ws);
    unsigned short* kb  = (unsigned short*)(ws + (8u << 20));
    unsigned short* vtg = (unsigned short*)(ws + (16u << 20));
    unsigned short* vc  = (unsigned short*)(ws + (24u << 20));
    unsigned short* Wto = (unsigned short*)(ws + (32u << 20));
    unsigned short* Wtq = (unsigned short*)(ws + (34u << 20));
    unsigned short* Wtk = (unsigned short*)(ws + (36u << 20));
    unsigned short* Wtv = (unsigned short*)(ws + (38u << 20));
    unsigned short* ctx = vc;                       // aliases vc (dead by then)
    float* vtail        = (float*)Wtq;              // aliases Wtq (dead by then)

    dim3 blk(256);
    k_cvt<<<dim3(1024, 3), blk, 0, stream>>>(Q, K, V, qc, kc, vc);
    k_wt<<<dim3(16, 16, 4), blk, 0, stream>>>(Wq, Wk, Wv, Wo, Wtq, Wtk, Wtv, Wto);
    k_gemm_bf16<1><<<dim3(M / 128, D / 128, 3), blk, 0, stream>>>(
        qc, kc, vc, Wtq, Wtk, Wtv, bq, bk, bv, qb, kb, vtg);
    k_vtail<<<dim3((B * D) / 4), blk, 0, stream>>>(vtg, vtail);
    k_attn<<<dim3(512), blk, 0, stream>>>(qb, kb, vtg, vtail, ctx);
    k_gemm_bf16<0><<<dim3(M / 128, D / 128, 1), blk, 0, stream>>>(
        ctx, ctx, ctx, Wto, Wto, Wto, bo, bo, bo, d_out, d_out, d_out);
}

// Round 14
// 124.496 us; speedup vs baseline: 1.8435x; 1.0053x over previous
//
#include <hip/hip_runtime.h>
#include <hip/hip_bf16.h>
#include <stdint.h>

#define DI __device__ __forceinline__

typedef __bf16 bf16x8 __attribute__((ext_vector_type(8)));
typedef float f32x4 __attribute__((ext_vector_type(4)));
typedef unsigned short ushortx8 __attribute__((ext_vector_type(8)));

// fp32 -> bf16 round-to-nearest-even (scalar path)
DI unsigned short f2bf(float f) {
    unsigned int u = __builtin_bit_cast(unsigned int, f);
    u += 0x7fffu + ((u >> 16) & 1u);
    return (unsigned short)(u >> 16);
}

// packed fp32x2 -> bf16x2 (1 VALU op). lo -> bits 0-15, hi -> bits 16-31.
DI unsigned int cvt_pk_bf16(float lo, float hi) {
    unsigned int r;
    asm("v_cvt_pk_bf16_f32 %0, %1, %2" : "=v"(r) : "v"(lo), "v"(hi));
    return r;
}

DI f32x4 mfma_16x16x32_bf16(bf16x8 a, bf16x8 b, f32x4 c) {
    return __builtin_amdgcn_mfma_f32_16x16x32_bf16(a, b, c, 0, 0, 0);
}

// async global->LDS, 16B per lane. LDS dest: wave-uniform base + lane*16.
DI void gload16(const unsigned short* g, unsigned short* l) {
    __builtin_amdgcn_global_load_lds(
        (const __attribute__((address_space(1))) void*)g,
        (__attribute__((address_space(3))) void*)l, 16, 0, 0);
}

// ---------------------------------------------------------------------------
// k_prep: fused prep. Blocks 0..3071: fp32->bf16 cvt of Q/K/V (z = bx/1024).
// Blocks 3072..4095: W fp32 [k][n] -> Wt bf16 [n][k] transpose (4 matrices,
// 64x64 tiles via XOR-swizzled LDS). One dispatch instead of two.
// ---------------------------------------------------------------------------
__global__ __launch_bounds__(256) void k_prep(
    const float* __restrict__ Q, const float* __restrict__ K, const float* __restrict__ V,
    unsigned short* __restrict__ qc, unsigned short* __restrict__ kc, unsigned short* __restrict__ vc,
    const float* __restrict__ w0, const float* __restrict__ w1,
    const float* __restrict__ w2, const float* __restrict__ w3,
    unsigned short* __restrict__ o0, unsigned short* __restrict__ o1,
    unsigned short* __restrict__ o2, unsigned short* __restrict__ o3)
{
    constexpr int N = 1024;
    __shared__ unsigned short L[64 * 64];
    const int bx = blockIdx.x;
    const int tid = threadIdx.x;

    if (bx < 3072) {
        // ---- cvt path ----
        const int z = bx >> 10;
        const int ib = bx & 1023;
        const float* s = z == 0 ? Q : z == 1 ? K : V;
        unsigned short* d = z == 0 ? qc : z == 1 ? kc : vc;
        const int i0 = ib * 256 + tid;
        #pragma unroll
        for (int it = 0; it < 4; ++it) {
            const int i = i0 + it * 262144;
            const float4 v = reinterpret_cast<const float4*>(s)[i];
            uint2 pk;
            pk.x = cvt_pk_bf16(v.x, v.y);
            pk.y = cvt_pk_bf16(v.z, v.w);
            reinterpret_cast<uint2*>(d)[i] = pk;
        }
    } else {
        // ---- weight-transpose path ----
        const int r4 = bx - 3072;
        const int z = r4 >> 8;
        const int tile = r4 & 255;
        const float* W = z == 0 ? w0 : z == 1 ? w1 : z == 2 ? w2 : w3;
        unsigned short* O = z == 0 ? o0 : z == 1 ? o1 : z == 2 ? o2 : o3;
        const int k0 = (tile >> 4) * 64, n0 = (tile & 15) * 64;

        const int r = tid >> 2, cbase = (tid & 3) * 16;
        #pragma unroll
        for (int i = 0; i < 4; ++i) {
            const int c = cbase + i * 4;
            const float4 v = *reinterpret_cast<const float4*>(&W[(size_t)(k0 + r) * N + n0 + c]);
            uint2 pk;
            pk.x = cvt_pk_bf16(v.x, v.y);
            pk.y = cvt_pk_bf16(v.z, v.w);
            const int byte = r * 128 + ((c * 2) ^ ((r & 7) << 4));
            *reinterpret_cast<uint2*>(reinterpret_cast<char*>(L) + byte) = pk;
        }
        __syncthreads();

        const int n = tid >> 2, kc2 = (tid & 3) * 16;
        ushortx8 v0, v1;
        #pragma unroll
        for (int j = 0; j < 8; ++j) {
            const int ka = kc2 + j, kb2 = kc2 + 8 + j;
            v0[j] = *reinterpret_cast<const unsigned short*>(
                reinterpret_cast<const char*>(L) + ka * 128 + ((n * 2) ^ ((ka & 7) << 4)));
            v1[j] = *reinterpret_cast<const unsigned short*>(
                reinterpret_cast<const char*>(L) + kb2 * 128 + ((n * 2) ^ ((kb2 & 7) << 4)));
        }
        unsigned short* op = &O[(size_t)(n0 + n) * N + k0 + kc2];
        *reinterpret_cast<ushortx8*>(op) = v0;
        *reinterpret_cast<ushortx8*>(op + 8) = v1;
    }
}

// ---------------------------------------------------------------------------
// bf16 GEMM, BK=64 (proven round-12): 16 barriers, 32 MFMA/step, both-sides
// swizzle (pre-swizzled global source + XOR'd ds_read). Conflicts = 0.
// ---------------------------------------------------------------------------
template <int MODE>
__global__ __launch_bounds__(256) void k_gemm_bf16(
    const unsigned short* __restrict__ A0, const unsigned short* __restrict__ A1,
    const unsigned short* __restrict__ A2,
    const unsigned short* __restrict__ B0, const unsigned short* __restrict__ B1,
    const unsigned short* __restrict__ B2,
    const float* __restrict__ bias0, const float* __restrict__ bias1,
    const float* __restrict__ bias2,
    void* C0, void* C1, void* C2)
{
    constexpr int K = 1024, N = 1024;
    const int z = MODE ? blockIdx.z : 0;
    const unsigned short* A  = z == 0 ? A0 : z == 1 ? A1 : A2;
    const unsigned short* Bt = z == 0 ? B0 : z == 1 ? B1 : B2;
    const float* bias        = z == 0 ? bias0 : z == 1 ? bias1 : bias2;
    void* C                  = z == 0 ? C0 : z == 1 ? C1 : C2;

    __shared__ unsigned short As[128 * 64];   // 16 KB, [row][k] 128-B rows
    __shared__ unsigned short Bs[128 * 64];

    const int tid  = threadIdx.x;
    const int lane = tid & 63;
    const int w    = tid >> 6;
    const int wr   = w >> 1, wc = w & 1;
    const int fr   = lane & 15, kg = lane >> 4;
    const int m0   = blockIdx.x * 128, n0 = blockIdx.y * 128;

    // staging: chunk = 8 rows (1 KB); lane covers row c*8+(l>>3), swizzled col
    const int c0    = w * 4;
    const int srow8 = lane >> 3;                       // 0..7
    const int sswz  = ((lane & 7) ^ (lane >> 3)) * 8;  // pre-swizzled k-offset

    f32x4 acc[4][4] = {};

    for (int t = 0; t < K / 64; ++t) {
        const int k0 = t * 64;
        #pragma unroll
        for (int it = 0; it < 4; ++it) {
            const int c = c0 + it;
            const int row = c * 8 + srow8;
            gload16(&A[(size_t)(m0 + row) * K + k0 + sswz], &As[c * 512]);
            gload16(&Bt[(size_t)(n0 + row) * K + k0 + sswz], &Bs[c * 512]);
        }
        __syncthreads();

        const int rsw = (fr & 7) << 4;   // read-side XOR (byte)
        #pragma unroll
        for (int kh = 0; kh < 2; ++kh) {
            bf16x8 af[4], bfj[4];
            #pragma unroll
            for (int i = 0; i < 4; ++i)
                af[i] = *reinterpret_cast<const bf16x8*>(
                    reinterpret_cast<const char*>(As) +
                    (wr * 64 + i * 16 + fr) * 128 + ((kh * 64 + kg * 16) ^ rsw));
            #pragma unroll
            for (int j = 0; j < 4; ++j)
                bfj[j] = *reinterpret_cast<const bf16x8*>(
                    reinterpret_cast<const char*>(Bs) +
                    (wc * 64 + j * 16 + fr) * 128 + ((kh * 64 + kg * 16) ^ rsw));
            #pragma unroll
            for (int i = 0; i < 4; ++i)
                #pragma unroll
                for (int j = 0; j < 4; ++j)
                    acc[i][j] = mfma_16x16x32_bf16(af[i], bfj[j], acc[i][j]);
        }
        __syncthreads();
    }

    if (MODE == 1 && z == 2) {
        unsigned short* vt = reinterpret_cast<unsigned short*>(C);
        #pragma unroll
        for (int i = 0; i < 4; ++i) {
            const int m = m0 + wr * 64 + i * 16 + kg * 4;
            const int bb = m >> 11, s = m & 2047;
            #pragma unroll
            for (int j = 0; j < 4; ++j) {
                const int n = n0 + wc * 64 + j * 16 + fr;
                const float bv = bias[n];
                uint2 pk;
                pk.x = cvt_pk_bf16(acc[i][j][0] + bv, acc[i][j][1] + bv);
                pk.y = cvt_pk_bf16(acc[i][j][2] + bv, acc[i][j][3] + bv);
                *reinterpret_cast<uint2*>(&vt[((size_t)(bb * 1024 + n)) * 2048 + s]) = pk;
            }
        }
    } else if (MODE == 1) {
        const float sc = (z == 0) ? 0.125f : 1.0f;
        unsigned short* Cb = reinterpret_cast<unsigned short*>(C);
        #pragma unroll
        for (int i = 0; i < 4; ++i) {
            const int m = m0 + wr * 64 + i * 16 + kg * 4;
            #pragma unroll
            for (int j = 0; j < 4; ++j) {
                const int n = n0 + wc * 64 + j * 16 + fr;
                const float bv = bias[n];
                const unsigned int p0 = cvt_pk_bf16((acc[i][j][0] + bv) * sc, (acc[i][j][1] + bv) * sc);
                const unsigned int p1 = cvt_pk_bf16((acc[i][j][2] + bv) * sc, (acc[i][j][3] + bv) * sc);
                Cb[(size_t)(m + 0) * N + n] = (unsigned short)p0;
                Cb[(size_t)(m + 1) * N + n] = (unsigned short)(p0 >> 16);
                Cb[(size_t)(m + 2) * N + n] = (unsigned short)p1;
                Cb[(size_t)(m + 3) * N + n] = (unsigned short)(p1 >> 16);
            }
        }
    } else {
        float* Cf = reinterpret_cast<float*>(C);
        #pragma unroll
        for (int i = 0; i < 4; ++i) {
            const int m = m0 + wr * 64 + i * 16 + kg * 4;
            #pragma unroll
            for (int j = 0; j < 4; ++j) {
                const int n = n0 + wc * 64 + j * 16 + fr;
                const float bv = bias[n];
                #pragma unroll
                for (int r = 0; r < 4; ++r)
                    Cf[(size_t)(m + r) * N + n] = acc[i][j][r] + bv;
            }
        }
    }
}

// ---------------------------------------------------------------------------
// V tail suffix sums (unchanged).
// ---------------------------------------------------------------------------
__global__ __launch_bounds__(256) void k_vtail(
    const unsigned short* __restrict__ vt, float* __restrict__ vtail)
{
    const int row = blockIdx.x * 4 + (threadIdx.x >> 6);
    const int l = threadIdx.x & 63;
    const unsigned short* p = &vt[(size_t)row * 2048 + l * 32];
    float s = 0.f;
    #pragma unroll
    for (int i = 0; i < 4; ++i) {
        ushortx8 v = *reinterpret_cast<const ushortx8*>(&p[i * 8]);
        #pragma unroll
        for (int e = 0; e < 8; ++e)
            s += __builtin_bit_cast(float, (unsigned int)v[e] << 16);
    }
    #pragma unroll
    for (int off = 1; off < 64; off <<= 1) {
        const float t = __shfl_down(s, off, 64);
        s += (l + off < 64) ? t : 0.f;
    }
    float tv = __shfl(s, (2 * l + 2) & 63, 64);
    if (l == 31) tv = 0.f;
    if (l < 32) vtail[(size_t)row * 32 + l] = tv;
}

// ---------------------------------------------------------------------------
// Attention (round-13 proven: pair balancing + XCD chunked swizzle + dbuf
// swizzled LDS + T14 prefetch) + T5 setprio around MFMA clusters (m191:
// +4-7% in the independent-blocks regime; NOT applied to lockstep GEMM).
// ---------------------------------------------------------------------------
template <bool MASK>
DI void attn_tile(const unsigned char* KsB, const unsigned char* VtsB,
                  unsigned char* PB, bf16x8 qf0, bf16x8 qf1,
                  f32x4 (&o)[4], float& lsum, int w, int fr, int kg)
{
    const int sw = (fr & 7) << 4;
    #pragma unroll
    for (int j = 0; j < 4; ++j) {
        const int row = j * 16 + fr;
        const bf16x8 kf0 = *reinterpret_cast<const bf16x8*>(KsB + row * 128 + ((kg * 16) ^ sw));
        const bf16x8 kf1 = *reinterpret_cast<const bf16x8*>(KsB + row * 128 + ((64 + kg * 16) ^ sw));
        f32x4 s = {0.f, 0.f, 0.f, 0.f};
        __builtin_amdgcn_s_setprio(1);
        s = mfma_16x16x32_bf16(kf0, qf0, s);   // swapped: A=K rows (keys), B=Q
        s = mfma_16x16x32_bf16(kf1, qf1, s);
        __builtin_amdgcn_s_setprio(0);
        float p[4];
        #pragma unroll
        for (int r = 0; r < 4; ++r) {
            float e = __expf(s[r]);
            if (MASK && (j * 16 + kg * 4 + r > w * 16 + fr)) e = 1.0f;  // exp(-1e-8)==1.0f
            p[r] = e;
            lsum += e;
        }
        uint2 pk;
        pk.x = cvt_pk_bf16(p[0], p[1]);
        pk.y = cvt_pk_bf16(p[2], p[3]);
        *reinterpret_cast<uint2*>(PB + fr * 128 + ((j * 32 + kg * 8) ^ sw)) = pk;
    }
    __builtin_amdgcn_s_setprio(1);
    #pragma unroll
    for (int kk = 0; kk < 2; ++kk) {
        const bf16x8 pf = *reinterpret_cast<const bf16x8*>(PB + fr * 128 + ((kk * 64 + kg * 16) ^ sw));
        #pragma unroll
        for (int n = 0; n < 4; ++n) {
            const int vrow = n * 16 + fr;
            const bf16x8 vf = *reinterpret_cast<const bf16x8*>(VtsB + vrow * 128 + ((kk * 64 + kg * 16) ^ sw));
            o[n] = mfma_16x16x32_bf16(pf, vf, o[n]);
        }
    }
    __builtin_amdgcn_s_setprio(0);
}

DI void attn_sweep(int qt,
                   const unsigned short* __restrict__ qp,
                   const unsigned short* __restrict__ kp,
                   const unsigned short* __restrict__ vt,
                   const float* __restrict__ vtail,
                   unsigned short* __restrict__ ctx,
                   unsigned char (*KsB)[64 * 128], unsigned char (*VtsB)[64 * 128],
                   unsigned char* PB, size_t baseQ, size_t baseV, int b, int h,
                   int w, int fr, int kg, int sr, int sc8, int wb0, int wb1)
{
    constexpr int S = 2048, D = 1024;
    const int q0 = qt * 64 + w * 16;

    bf16x8 qf0, qf1;
    {
        const size_t roff = baseQ + (size_t)(q0 + fr) * D;
        qf0 = *reinterpret_cast<const bf16x8*>(&qp[roff + kg * 8]);
        qf1 = *reinterpret_cast<const bf16x8*>(&qp[roff + 32 + kg * 8]);
    }

    f32x4 o[4] = {};
    float lsum = 0.f;
    const int NT = qt + 1;

    // prologue: stage tile 0 into buffer 0
    {
        const ushortx8 kr0 = *reinterpret_cast<const ushortx8*>(&kp[baseQ + (size_t)sr * D + sc8]);
        const ushortx8 kr1 = *reinterpret_cast<const ushortx8*>(&kp[baseQ + (size_t)(sr + 32) * D + sc8]);
        const ushortx8 vr0 = *reinterpret_cast<const ushortx8*>(&vt[baseV + (size_t)sr * S + sc8]);
        const ushortx8 vr1 = *reinterpret_cast<const ushortx8*>(&vt[baseV + (size_t)(sr + 32) * S + sc8]);
        *reinterpret_cast<ushortx8*>(KsB[0] + wb0)  = kr0;
        *reinterpret_cast<ushortx8*>(KsB[0] + wb1)  = kr1;
        *reinterpret_cast<ushortx8*>(VtsB[0] + wb0) = vr0;
        *reinterpret_cast<ushortx8*>(VtsB[0] + wb1) = vr1;
    }
    __syncthreads();

    for (int t = 0; t < NT; ++t) {
        const int cur = t & 1;
        const bool more = (t + 1 < NT);
        ushortx8 nk0, nk1, nv0, nv1;
        if (more) {   // T14: issue next-tile loads before compute
            const int kt1 = (t + 1) * 64;
            nk0 = *reinterpret_cast<const ushortx8*>(&kp[baseQ + (size_t)(kt1 + sr) * D + sc8]);
            nk1 = *reinterpret_cast<const ushortx8*>(&kp[baseQ + (size_t)(kt1 + sr + 32) * D + sc8]);
            nv0 = *reinterpret_cast<const ushortx8*>(&vt[baseV + (size_t)sr * S + kt1 + sc8]);
            nv1 = *reinterpret_cast<const ushortx8*>(&vt[baseV + (size_t)(sr + 32) * S + kt1 + sc8]);
        }
        if (more)
            attn_tile<false>(KsB[cur], VtsB[cur], PB, qf0, qf1, o, lsum, w, fr, kg);
        else
            attn_tile<true>(KsB[cur], VtsB[cur], PB, qf0, qf1, o, lsum, w, fr, kg);
        if (more) {   // write next tile into the other buffer (no extra barrier)
            const int nxt = cur ^ 1;
            *reinterpret_cast<ushortx8*>(KsB[nxt] + wb0)  = nk0;
            *reinterpret_cast<ushortx8*>(KsB[nxt] + wb1)  = nk1;
            *reinterpret_cast<ushortx8*>(VtsB[nxt] + wb0) = nv0;
            *reinterpret_cast<ushortx8*>(VtsB[nxt] + wb1) = nv1;
        }
        __syncthreads();
    }

    // full row sums: combine the 4 key-groups, add analytic tail count
    lsum += __shfl_xor(lsum, 16, 64);
    lsum += __shfl_xor(lsum, 32, 64);
    lsum += (float)(S - (qt + 1) * 64);

    float lq[4];
    #pragma unroll
    for (int r = 0; r < 4; ++r) lq[r] = __shfl(lsum, kg * 4 + r, 64);

    float tl[4];
    #pragma unroll
    for (int n = 0; n < 4; ++n)
        tl[n] = vtail[((size_t)(b * 1024) + h * 64 + n * 16 + fr) * 32 + qt];

    #pragma unroll
    for (int n = 0; n < 4; ++n)
        #pragma unroll
        for (int r = 0; r < 4; ++r) {
            const int qrow = q0 + kg * 4 + r;
            ctx[baseQ + (size_t)qrow * D + n * 16 + fr] = f2bf((o[n][r] + tl[n]) / lq[r]);
        }
}

__global__ __launch_bounds__(256, 2) void k_attn(
    const unsigned short* __restrict__ qp,
    const unsigned short* __restrict__ kp,
    const unsigned short* __restrict__ vt,
    const float* __restrict__ vtail,
    unsigned short* __restrict__ ctx)
{
    constexpr int S = 2048, D = 1024;
    // T1 chunked XCD swizzle: G = (L%8)*64 + L/8 (bijective, 512 = 8*64):
    // each XCD's 64 resident blocks = 4 complete (h,b) panel groups (2 MB).
    const int L = blockIdx.x;
    const int G = (L & 7) * 64 + (L >> 3);
    const int p = G & 15;            // pair index 0..15
    const int h = (G >> 4) & 15;     // head
    const int b = G >> 8;            // batch

    __shared__ alignas(16) unsigned char KsB[2][64 * 128];     // dbuf K, swizzled
    __shared__ alignas(16) unsigned char VtsB[2][64 * 128];    // dbuf V, swizzled
    __shared__ alignas(16) unsigned char PlsB[4 * 16 * 128];   // per-wave P

    const int tid  = threadIdx.x;
    const int lane = tid & 63, w = tid >> 6;
    const int fr   = lane & 15, kg = lane >> 4;
    unsigned char* PB = PlsB + w * 2048;

    const size_t baseQ = ((size_t)b * S) * D + (size_t)h * 64;
    const size_t baseV = ((size_t)b * D + (size_t)h * 64) * S;

    const int sr  = tid >> 3;          // staging row 0..31
    const int sc8 = (tid & 7) * 8;     // element offset (8 bf16)
    const int wb0 = sr * 128 + (((tid & 7) * 16) ^ ((sr & 7) << 4));
    const int wb1 = (sr + 32) * 128 + (((tid & 7) * 16) ^ (((sr + 32) & 7) << 4));

    // pair (31-p, p): total key-tiles = (32-p) + (p+1) = 33, uniform
    attn_sweep(31 - p, qp, kp, vt, vtail, ctx, KsB, VtsB, PB,
               baseQ, baseV, b, h, w, fr, kg, sr, sc8, wb0, wb1);
    attn_sweep(p, qp, kp, vt, vtail, ctx, KsB, VtsB, PB,
               baseQ, baseV, b, h, w, fr, kg, sr, sc8, wb0, wb1);
}

// ---------------------------------------------------------------------------
extern "C" void kernel_launch(void* const* d_in, const int* in_sizes, int n_in,
                              void* d_out, int out_size, void* d_ws, size_t ws_size,
                              hipStream_t stream) {
    constexpr int B = 2, S = 2048, D = 1024;
    constexpr int M = B * S;                 // 4096
    constexpr size_t MD = (size_t)M * D;     // 4M elements

    const float* Q  = (const float*)d_in[0];
    const float* K  = (const float*)d_in[1];
    const float* V  = (const float*)d_in[2];
    const float* Wq = (const float*)d_in[4];
    const float* bq = (const float*)d_in[5];
    const float* Wk = (const float*)d_in[6];
    const float* bk = (const float*)d_in[7];
    const float* Wv = (const float*)d_in[8];
    const float* bv = (const float*)d_in[9];
    const float* Wo = (const float*)d_in[10];
    const float* bo = (const float*)d_in[11];

    // d_out (16 MiB, dead until final GEMM): qc (8 MiB) + kc (8 MiB)
    unsigned short* qc = (unsigned short*)d_out;
    unsigned short* kc = qc + MD;
    // d_ws (40 MiB): qb, kb, vtg, vc/ctx (8 MiB each) + Wto/Wtq/Wtk/Wtv (2 MiB each)
    char* ws = (char*)d_ws;
    unsigned short* qb  = (unsigned short*)(ws);
    unsigned short* kb  = (unsigned short*)(ws + (8u << 20));
    unsigned short* vtg = (unsigned short*)(ws + (16u << 20));
    unsigned short* vc  = (unsigned short*)(ws + (24u << 20));
    unsigned short* Wto = (unsigned short*)(ws + (32u << 20));
    unsigned short* Wtq = (unsigned short*)(ws + (34u << 20));
    unsigned short* Wtk = (unsigned short*)(ws + (36u << 20));
    unsigned short* Wtv = (unsigned short*)(ws + (38u << 20));
    unsigned short* ctx = vc;                       // aliases vc (dead by then)
    float* vtail        = (float*)Wtq;              // aliases Wtq (dead by then)

    dim3 blk(256);
    k_prep<<<dim3(4096), blk, 0, stream>>>(
        Q, K, V, qc, kc, vc, Wq, Wk, Wv, Wo, Wtq, Wtk, Wtv, Wto);
    k_gemm_bf16<1><<<dim3(M / 128, D / 128, 3), blk, 0, stream>>>(
        qc, kc, vc, Wtq, Wtk, Wtv, bq, bk, bv, qb, kb, vtg);
    k_vtail<<<dim3((B * D) / 4), blk, 0, stream>>>(vtg, vtail);
    k_attn<<<dim3(512), blk, 0, stream>>>(qb, kb, vtg, vtail, ctx);
    k_gemm_bf16<0><<<dim3(M / 128, D / 128, 1), blk, 0, stream>>>(
        ctx, ctx, ctx, Wto, Wto, Wto, bo, bo, bo, d_out, d_out, d_out);
}

// Round 15
// 123.294 us; speedup vs baseline: 1.8615x; 1.0097x over previous
//
#include <hip/hip_runtime.h>
#include <hip/hip_bf16.h>
#include <stdint.h>
#include <math.h>

#define DI __device__ __forceinline__

typedef __bf16 bf16x8 __attribute__((ext_vector_type(8)));
typedef float f32x4 __attribute__((ext_vector_type(4)));
typedef unsigned short ushortx8 __attribute__((ext_vector_type(8)));

// fp32 -> bf16 round-to-nearest-even (scalar path)
DI unsigned short f2bf(float f) {
    unsigned int u = __builtin_bit_cast(unsigned int, f);
    u += 0x7fffu + ((u >> 16) & 1u);
    return (unsigned short)(u >> 16);
}

// packed fp32x2 -> bf16x2 (1 VALU op). lo -> bits 0-15, hi -> bits 16-31.
DI unsigned int cvt_pk_bf16(float lo, float hi) {
    unsigned int r;
    asm("v_cvt_pk_bf16_f32 %0, %1, %2" : "=v"(r) : "v"(lo), "v"(hi));
    return r;
}

DI f32x4 mfma_16x16x32_bf16(bf16x8 a, bf16x8 b, f32x4 c) {
    return __builtin_amdgcn_mfma_f32_16x16x32_bf16(a, b, c, 0, 0, 0);
}

// async global->LDS, 16B per lane. LDS dest: wave-uniform base + lane*16.
DI void gload16(const unsigned short* g, unsigned short* l) {
    __builtin_amdgcn_global_load_lds(
        (const __attribute__((address_space(1))) void*)g,
        (__attribute__((address_space(3))) void*)l, 16, 0, 0);
}

// ---------------------------------------------------------------------------
// k_prep: fused prep (round-14 proven). Blocks 0..3071: fp32->bf16 cvt of
// Q/K/V. Blocks 3072..4095: W -> Wt bf16 transpose (4 matrices, 64x64 tiles).
// ---------------------------------------------------------------------------
__global__ __launch_bounds__(256) void k_prep(
    const float* __restrict__ Q, const float* __restrict__ K, const float* __restrict__ V,
    unsigned short* __restrict__ qc, unsigned short* __restrict__ kc, unsigned short* __restrict__ vc,
    const float* __restrict__ w0, const float* __restrict__ w1,
    const float* __restrict__ w2, const float* __restrict__ w3,
    unsigned short* __restrict__ o0, unsigned short* __restrict__ o1,
    unsigned short* __restrict__ o2, unsigned short* __restrict__ o3)
{
    constexpr int N = 1024;
    __shared__ unsigned short L[64 * 64];
    const int bx = blockIdx.x;
    const int tid = threadIdx.x;

    if (bx < 3072) {
        const int z = bx >> 10;
        const int ib = bx & 1023;
        const float* s = z == 0 ? Q : z == 1 ? K : V;
        unsigned short* d = z == 0 ? qc : z == 1 ? kc : vc;
        const int i0 = ib * 256 + tid;
        #pragma unroll
        for (int it = 0; it < 4; ++it) {
            const int i = i0 + it * 262144;
            const float4 v = reinterpret_cast<const float4*>(s)[i];
            uint2 pk;
            pk.x = cvt_pk_bf16(v.x, v.y);
            pk.y = cvt_pk_bf16(v.z, v.w);
            reinterpret_cast<uint2*>(d)[i] = pk;
        }
    } else {
        const int r4 = bx - 3072;
        const int z = r4 >> 8;
        const int tile = r4 & 255;
        const float* W = z == 0 ? w0 : z == 1 ? w1 : z == 2 ? w2 : w3;
        unsigned short* O = z == 0 ? o0 : z == 1 ? o1 : z == 2 ? o2 : o3;
        const int k0 = (tile >> 4) * 64, n0 = (tile & 15) * 64;

        const int r = tid >> 2, cbase = (tid & 3) * 16;
        #pragma unroll
        for (int i = 0; i < 4; ++i) {
            const int c = cbase + i * 4;
            const float4 v = *reinterpret_cast<const float4*>(&W[(size_t)(k0 + r) * N + n0 + c]);
            uint2 pk;
            pk.x = cvt_pk_bf16(v.x, v.y);
            pk.y = cvt_pk_bf16(v.z, v.w);
            const int byte = r * 128 + ((c * 2) ^ ((r & 7) << 4));
            *reinterpret_cast<uint2*>(reinterpret_cast<char*>(L) + byte) = pk;
        }
        __syncthreads();

        const int n = tid >> 2, kc2 = (tid & 3) * 16;
        ushortx8 v0, v1;
        #pragma unroll
        for (int j = 0; j < 8; ++j) {
            const int ka = kc2 + j, kb2 = kc2 + 8 + j;
            v0[j] = *reinterpret_cast<const unsigned short*>(
                reinterpret_cast<const char*>(L) + ka * 128 + ((n * 2) ^ ((ka & 7) << 4)));
            v1[j] = *reinterpret_cast<const unsigned short*>(
                reinterpret_cast<const char*>(L) + kb2 * 128 + ((n * 2) ^ ((kb2 & 7) << 4)));
        }
        unsigned short* op = &O[(size_t)(n0 + n) * N + k0 + kc2];
        *reinterpret_cast<ushortx8*>(op) = v0;
        *reinterpret_cast<ushortx8*>(op + 8) = v1;
    }
}

// ---------------------------------------------------------------------------
// bf16 GEMM, BK=64, both-sides swizzle (proven round-12; conflicts = 0).
// BN template: 128 (QKV, 4-frag wave cols) or 64 (out-proj: doubles grid to
// 512 blocks = 2 blocks/CU -- fixes the 1-block/CU occupancy starvation).
// MODE 1 z==0 epilogue scale now folds log2(e) so attn can use exp2 directly.
// ---------------------------------------------------------------------------
template <int MODE, int BN>
__global__ __launch_bounds__(256) void k_gemm_bf16(
    const unsigned short* __restrict__ A0, const unsigned short* __restrict__ A1,
    const unsigned short* __restrict__ A2,
    const unsigned short* __restrict__ B0, const unsigned short* __restrict__ B1,
    const unsigned short* __restrict__ B2,
    const float* __restrict__ bias0, const float* __restrict__ bias1,
    const float* __restrict__ bias2,
    void* C0, void* C1, void* C2)
{
    constexpr int K = 1024, N = 1024;
    constexpr int NJ = BN / 32;          // wave-col fragments
    const int z = MODE ? blockIdx.z : 0;
    const unsigned short* A  = z == 0 ? A0 : z == 1 ? A1 : A2;
    const unsigned short* Bt = z == 0 ? B0 : z == 1 ? B1 : B2;
    const float* bias        = z == 0 ? bias0 : z == 1 ? bias1 : bias2;
    void* C                  = z == 0 ? C0 : z == 1 ? C1 : C2;

    __shared__ unsigned short As[128 * 64];      // [row][k] 128-B rows
    __shared__ unsigned short Bs[BN * 64];

    const int tid  = threadIdx.x;
    const int lane = tid & 63;
    const int w    = tid >> 6;
    const int wr   = w >> 1, wc = w & 1;
    const int fr   = lane & 15, kg = lane >> 4;
    const int m0   = blockIdx.x * 128, n0 = blockIdx.y * BN;

    // staging: chunk = 8 rows (1 KB); lane covers row c*8+(l>>3), swizzled col
    const int srow8 = lane >> 3;                       // 0..7
    const int sswz  = ((lane & 7) ^ (lane >> 3)) * 8;  // pre-swizzled k-offset

    f32x4 acc[4][NJ] = {};

    for (int t = 0; t < K / 64; ++t) {
        const int k0 = t * 64;
        #pragma unroll
        for (int it = 0; it < 4; ++it) {
            const int c = w * 4 + it;
            gload16(&A[(size_t)(m0 + c * 8 + srow8) * K + k0 + sswz], &As[c * 512]);
            if (BN == 128)
                gload16(&Bt[(size_t)(n0 + c * 8 + srow8) * K + k0 + sswz], &Bs[c * 512]);
        }
        if (BN == 64) {
            #pragma unroll
            for (int it = 0; it < 2; ++it) {
                const int c = w * 2 + it;    // 8 chunks cover 64 rows
                gload16(&Bt[(size_t)(n0 + c * 8 + srow8) * K + k0 + sswz], &Bs[c * 512]);
            }
        }
        __syncthreads();

        const int rsw = (fr & 7) << 4;   // read-side XOR (byte)
        #pragma unroll
        for (int kh = 0; kh < 2; ++kh) {
            bf16x8 af[4], bfj[NJ];
            #pragma unroll
            for (int i = 0; i < 4; ++i)
                af[i] = *reinterpret_cast<const bf16x8*>(
                    reinterpret_cast<const char*>(As) +
                    (wr * 64 + i * 16 + fr) * 128 + ((kh * 64 + kg * 16) ^ rsw));
            #pragma unroll
            for (int j = 0; j < NJ; ++j)
                bfj[j] = *reinterpret_cast<const bf16x8*>(
                    reinterpret_cast<const char*>(Bs) +
                    (wc * (BN / 2) + j * 16 + fr) * 128 + ((kh * 64 + kg * 16) ^ rsw));
            #pragma unroll
            for (int i = 0; i < 4; ++i)
                #pragma unroll
                for (int j = 0; j < NJ; ++j)
                    acc[i][j] = mfma_16x16x32_bf16(af[i], bfj[j], acc[i][j]);
        }
        __syncthreads();
    }

    if (MODE == 1 && z == 2) {
        // V: store transposed per batch: vt[(bb*1024 + n)*2048 + s]
        unsigned short* vt = reinterpret_cast<unsigned short*>(C);
        #pragma unroll
        for (int i = 0; i < 4; ++i) {
            const int m = m0 + wr * 64 + i * 16 + kg * 4;
            const int bb = m >> 11, s = m & 2047;
            #pragma unroll
            for (int j = 0; j < NJ; ++j) {
                const int n = n0 + wc * (BN / 2) + j * 16 + fr;
                const float bv = bias[n];
                uint2 pk;
                pk.x = cvt_pk_bf16(acc[i][j][0] + bv, acc[i][j][1] + bv);
                pk.y = cvt_pk_bf16(acc[i][j][2] + bv, acc[i][j][3] + bv);
                *reinterpret_cast<uint2*>(&vt[((size_t)(bb * 1024 + n)) * 2048 + s]) = pk;
            }
        }
    } else if (MODE == 1) {
        // z==0 (Q): fold 1/sqrt(64) * log2(e) so attention uses native exp2.
        const float sc = (z == 0) ? 0.125f * 1.44269504088896340736f : 1.0f;
        unsigned short* Cb = reinterpret_cast<unsigned short*>(C);
        #pragma unroll
        for (int i = 0; i < 4; ++i) {
            const int m = m0 + wr * 64 + i * 16 + kg * 4;
            #pragma unroll
            for (int j = 0; j < NJ; ++j) {
                const int n = n0 + wc * (BN / 2) + j * 16 + fr;
                const float bv = bias[n];
                const unsigned int p0 = cvt_pk_bf16((acc[i][j][0] + bv) * sc, (acc[i][j][1] + bv) * sc);
                const unsigned int p1 = cvt_pk_bf16((acc[i][j][2] + bv) * sc, (acc[i][j][3] + bv) * sc);
                Cb[(size_t)(m + 0) * N + n] = (unsigned short)p0;
                Cb[(size_t)(m + 1) * N + n] = (unsigned short)(p0 >> 16);
                Cb[(size_t)(m + 2) * N + n] = (unsigned short)p1;
                Cb[(size_t)(m + 3) * N + n] = (unsigned short)(p1 >> 16);
            }
        }
    } else {
        float* Cf = reinterpret_cast<float*>(C);
        #pragma unroll
        for (int i = 0; i < 4; ++i) {
            const int m = m0 + wr * 64 + i * 16 + kg * 4;
            #pragma unroll
            for (int j = 0; j < NJ; ++j) {
                const int n = n0 + wc * (BN / 2) + j * 16 + fr;
                const float bv = bias[n];
                #pragma unroll
                for (int r = 0; r < 4; ++r)
                    Cf[(size_t)(m + r) * N + n] = acc[i][j][r] + bv;
            }
        }
    }
}

// ---------------------------------------------------------------------------
// V tail suffix sums (unchanged).
// ---------------------------------------------------------------------------
__global__ __launch_bounds__(256) void k_vtail(
    const unsigned short* __restrict__ vt, float* __restrict__ vtail)
{
    const int row = blockIdx.x * 4 + (threadIdx.x >> 6);
    const int l = threadIdx.x & 63;
    const unsigned short* p = &vt[(size_t)row * 2048 + l * 32];
    float s = 0.f;
    #pragma unroll
    for (int i = 0; i < 4; ++i) {
        ushortx8 v = *reinterpret_cast<const ushortx8*>(&p[i * 8]);
        #pragma unroll
        for (int e = 0; e < 8; ++e)
            s += __builtin_bit_cast(float, (unsigned int)v[e] << 16);
    }
    #pragma unroll
    for (int off = 1; off < 64; off <<= 1) {
        const float t = __shfl_down(s, off, 64);
        s += (l + off < 64) ? t : 0.f;
    }
    float tv = __shfl(s, (2 * l + 2) & 63, 64);
    if (l == 31) tv = 0.f;
    if (l < 32) vtail[(size_t)row * 32 + l] = tv;
}

// ---------------------------------------------------------------------------
// Attention (round-13/14 proven: pair balancing + XCD chunked swizzle + dbuf
// swizzled LDS + T14 prefetch + T5 setprio). exp2 path: q pre-scaled by
// 0.125*log2(e) in projection -> exp2f lowers to bare v_exp_f32 (no per-score
// mul). Masked scores -> exp(-1e-8) == 1.0f exactly, unchanged.
// ---------------------------------------------------------------------------
template <bool MASK>
DI void attn_tile(const unsigned char* KsB, const unsigned char* VtsB,
                  unsigned char* PB, bf16x8 qf0, bf16x8 qf1,
                  f32x4 (&o)[4], float& lsum, int w, int fr, int kg)
{
    const int sw = (fr & 7) << 4;
    #pragma unroll
    for (int j = 0; j < 4; ++j) {
        const int row = j * 16 + fr;
        const bf16x8 kf0 = *reinterpret_cast<const bf16x8*>(KsB + row * 128 + ((kg * 16) ^ sw));
        const bf16x8 kf1 = *reinterpret_cast<const bf16x8*>(KsB + row * 128 + ((64 + kg * 16) ^ sw));
        f32x4 s = {0.f, 0.f, 0.f, 0.f};
        __builtin_amdgcn_s_setprio(1);
        s = mfma_16x16x32_bf16(kf0, qf0, s);   // swapped: A=K rows (keys), B=Q
        s = mfma_16x16x32_bf16(kf1, qf1, s);
        __builtin_amdgcn_s_setprio(0);
        float p[4];
        #pragma unroll
        for (int r = 0; r < 4; ++r) {
            float e = exp2f(s[r]);             // q pre-scaled by log2e -> native 2^x
            if (MASK && (j * 16 + kg * 4 + r > w * 16 + fr)) e = 1.0f;  // exp(-1e-8)==1.0f
            p[r] = e;
            lsum += e;
        }
        uint2 pk;
        pk.x = cvt_pk_bf16(p[0], p[1]);
        pk.y = cvt_pk_bf16(p[2], p[3]);
        *reinterpret_cast<uint2*>(PB + fr * 128 + ((j * 32 + kg * 8) ^ sw)) = pk;
    }
    __builtin_amdgcn_s_setprio(1);
    #pragma unroll
    for (int kk = 0; kk < 2; ++kk) {
        const bf16x8 pf = *reinterpret_cast<const bf16x8*>(PB + fr * 128 + ((kk * 64 + kg * 16) ^ sw));
        #pragma unroll
        for (int n = 0; n < 4; ++n) {
            const int vrow = n * 16 + fr;
            const bf16x8 vf = *reinterpret_cast<const bf16x8*>(VtsB + vrow * 128 + ((kk * 64 + kg * 16) ^ sw));
            o[n] = mfma_16x16x32_bf16(pf, vf, o[n]);
        }
    }
    __builtin_amdgcn_s_setprio(0);
}

DI void attn_sweep(int qt,
                   const unsigned short* __restrict__ qp,
                   const unsigned short* __restrict__ kp,
                   const unsigned short* __restrict__ vt,
                   const float* __restrict__ vtail,
                   unsigned short* __restrict__ ctx,
                   unsigned char (*KsB)[64 * 128], unsigned char (*VtsB)[64 * 128],
                   unsigned char* PB, size_t baseQ, size_t baseV, int b, int h,
                   int w, int fr, int kg, int sr, int sc8, int wb0, int wb1)
{
    constexpr int S = 2048, D = 1024;
    const int q0 = qt * 64 + w * 16;

    bf16x8 qf0, qf1;
    {
        const size_t roff = baseQ + (size_t)(q0 + fr) * D;
        qf0 = *reinterpret_cast<const bf16x8*>(&qp[roff + kg * 8]);
        qf1 = *reinterpret_cast<const bf16x8*>(&qp[roff + 32 + kg * 8]);
    }

    f32x4 o[4] = {};
    float lsum = 0.f;
    const int NT = qt + 1;

    // prologue: stage tile 0 into buffer 0
    {
        const ushortx8 kr0 = *reinterpret_cast<const ushortx8*>(&kp[baseQ + (size_t)sr * D + sc8]);
        const ushortx8 kr1 = *reinterpret_cast<const ushortx8*>(&kp[baseQ + (size_t)(sr + 32) * D + sc8]);
        const ushortx8 vr0 = *reinterpret_cast<const ushortx8*>(&vt[baseV + (size_t)sr * S + sc8]);
        const ushortx8 vr1 = *reinterpret_cast<const ushortx8*>(&vt[baseV + (size_t)(sr + 32) * S + sc8]);
        *reinterpret_cast<ushortx8*>(KsB[0] + wb0)  = kr0;
        *reinterpret_cast<ushortx8*>(KsB[0] + wb1)  = kr1;
        *reinterpret_cast<ushortx8*>(VtsB[0] + wb0) = vr0;
        *reinterpret_cast<ushortx8*>(VtsB[0] + wb1) = vr1;
    }
    __syncthreads();

    for (int t = 0; t < NT; ++t) {
        const int cur = t & 1;
        const bool more = (t + 1 < NT);
        ushortx8 nk0, nk1, nv0, nv1;
        if (more) {   // T14: issue next-tile loads before compute
            const int kt1 = (t + 1) * 64;
            nk0 = *reinterpret_cast<const ushortx8*>(&kp[baseQ + (size_t)(kt1 + sr) * D + sc8]);
            nk1 = *reinterpret_cast<const ushortx8*>(&kp[baseQ + (size_t)(kt1 + sr + 32) * D + sc8]);
            nv0 = *reinterpret_cast<const ushortx8*>(&vt[baseV + (size_t)sr * S + kt1 + sc8]);
            nv1 = *reinterpret_cast<const ushortx8*>(&vt[baseV + (size_t)(sr + 32) * S + kt1 + sc8]);
        }
        if (more)
            attn_tile<false>(KsB[cur], VtsB[cur], PB, qf0, qf1, o, lsum, w, fr, kg);
        else
            attn_tile<true>(KsB[cur], VtsB[cur], PB, qf0, qf1, o, lsum, w, fr, kg);
        if (more) {   // write next tile into the other buffer (no extra barrier)
            const int nxt = cur ^ 1;
            *reinterpret_cast<ushortx8*>(KsB[nxt] + wb0)  = nk0;
            *reinterpret_cast<ushortx8*>(KsB[nxt] + wb1)  = nk1;
            *reinterpret_cast<ushortx8*>(VtsB[nxt] + wb0) = nv0;
            *reinterpret_cast<ushortx8*>(VtsB[nxt] + wb1) = nv1;
        }
        __syncthreads();
    }

    // full row sums: combine the 4 key-groups, add analytic tail count
    lsum += __shfl_xor(lsum, 16, 64);
    lsum += __shfl_xor(lsum, 32, 64);
    lsum += (float)(S - (qt + 1) * 64);

    float rlq[4];
    #pragma unroll
    for (int r = 0; r < 4; ++r) rlq[r] = 1.0f / __shfl(lsum, kg * 4 + r, 64);

    float tl[4];
    #pragma unroll
    for (int n = 0; n < 4; ++n)
        tl[n] = vtail[((size_t)(b * 1024) + h * 64 + n * 16 + fr) * 32 + qt];

    #pragma unroll
    for (int n = 0; n < 4; ++n)
        #pragma unroll
        for (int r = 0; r < 4; ++r) {
            const int qrow = q0 + kg * 4 + r;
            ctx[baseQ + (size_t)qrow * D + n * 16 + fr] = f2bf((o[n][r] + tl[n]) * rlq[r]);
        }
}

__global__ __launch_bounds__(256, 2) void k_attn(
    const unsigned short* __restrict__ qp,
    const unsigned short* __restrict__ kp,
    const unsigned short* __restrict__ vt,
    const float* __restrict__ vtail,
    unsigned short* __restrict__ ctx)
{
    constexpr int S = 2048, D = 1024;
    // T1 chunked XCD swizzle: G = (L%8)*64 + L/8 (bijective, 512 = 8*64):
    // each XCD's 64 resident blocks = 4 complete (h,b) panel groups (2 MB).
    const int L = blockIdx.x;
    const int G = (L & 7) * 64 + (L >> 3);
    const int p = G & 15;            // pair index 0..15
    const int h = (G >> 4) & 15;     // head
    const int b = G >> 8;            // batch

    __shared__ alignas(16) unsigned char KsB[2][64 * 128];     // dbuf K, swizzled
    __shared__ alignas(16) unsigned char VtsB[2][64 * 128];    // dbuf V, swizzled
    __shared__ alignas(16) unsigned char PlsB[4 * 16 * 128];   // per-wave P

    const int tid  = threadIdx.x;
    const int lane = tid & 63, w = tid >> 6;
    const int fr   = lane & 15, kg = lane >> 4;
    unsigned char* PB = PlsB + w * 2048;

    const size_t baseQ = ((size_t)b * S) * D + (size_t)h * 64;
    const size_t baseV = ((size_t)b * D + (size_t)h * 64) * S;

    const int sr  = tid >> 3;          // staging row 0..31
    const int sc8 = (tid & 7) * 8;     // element offset (8 bf16)
    const int wb0 = sr * 128 + (((tid & 7) * 16) ^ ((sr & 7) << 4));
    const int wb1 = (sr + 32) * 128 + (((tid & 7) * 16) ^ (((sr + 32) & 7) << 4));

    // pair (31-p, p): total key-tiles = (32-p) + (p+1) = 33, uniform
    attn_sweep(31 - p, qp, kp, vt, vtail, ctx, KsB, VtsB, PB,
               baseQ, baseV, b, h, w, fr, kg, sr, sc8, wb0, wb1);
    attn_sweep(p, qp, kp, vt, vtail, ctx, KsB, VtsB, PB,
               baseQ, baseV, b, h, w, fr, kg, sr, sc8, wb0, wb1);
}

// ---------------------------------------------------------------------------
extern "C" void kernel_launch(void* const* d_in, const int* in_sizes, int n_in,
                              void* d_out, int out_size, void* d_ws, size_t ws_size,
                              hipStream_t stream) {
    constexpr int B = 2, S = 2048, D = 1024;
    constexpr int M = B * S;                 // 4096
    constexpr size_t MD = (size_t)M * D;     // 4M elements

    const float* Q  = (const float*)d_in[0];
    const float* K  = (const float*)d_in[1];
    const float* V  = (const float*)d_in[2];
    const float* Wq = (const float*)d_in[4];
    const float* bq = (const float*)d_in[5];
    const float* Wk = (const float*)d_in[6];
    const float* bk = (const float*)d_in[7];
    const float* Wv = (const float*)d_in[8];
    const float* bv = (const float*)d_in[9];
    const float* Wo = (const float*)d_in[10];
    const float* bo = (const float*)d_in[11];

    // d_out (16 MiB, dead until final GEMM): qc (8 MiB) + kc (8 MiB)
    unsigned short* qc = (unsigned short*)d_out;
    unsigned short* kc = qc + MD;
    // d_ws (40 MiB): qb, kb, vtg, vc/ctx (8 MiB each) + Wto/Wtq/Wtk/Wtv (2 MiB each)
    char* ws = (char*)d_ws;
    unsigned short* qb  = (unsigned short*)(ws);
    unsigned short* kb  = (unsigned short*)(ws + (8u << 20));
    unsigned short* vtg = (unsigned short*)(ws + (16u << 20));
    unsigned short* vc  = (unsigned short*)(ws + (24u << 20));
    unsigned short* Wto = (unsigned short*)(ws + (32u << 20));
    unsigned short* Wtq = (unsigned short*)(ws + (34u << 20));
    unsigned short* Wtk = (unsigned short*)(ws + (36u << 20));
    unsigned short* Wtv = (unsigned short*)(ws + (38u << 20));
    unsigned short* ctx = vc;                       // aliases vc (dead by then)
    float* vtail        = (float*)Wtq;              // aliases Wtq (dead by then)

    dim3 blk(256);
    k_prep<<<dim3(4096), blk, 0, stream>>>(
        Q, K, V, qc, kc, vc, Wq, Wk, Wv, Wo, Wtq, Wtk, Wtv, Wto);
    k_gemm_bf16<1, 128><<<dim3(M / 128, D / 128, 3), blk, 0, stream>>>(
        qc, kc, vc, Wtq, Wtk, Wtv, bq, bk, bv, qb, kb, vtg);
    k_vtail<<<dim3((B * D) / 4), blk, 0, stream>>>(vtg, vtail);
    k_attn<<<dim3(512), blk, 0, stream>>>(qb, kb, vtg, vtail, ctx);
    k_gemm_bf16<0, 64><<<dim3(M / 128, D / 64, 1), blk, 0, stream>>>(
        ctx, ctx, ctx, Wto, Wto, Wto, bo, bo, bo, d_out, d_out, d_out);
}